// Round 2
// baseline (262311.914 us; speedup 1.0000x reference)
//
#include <hip/hip_runtime.h>
#include <hip/hip_cooperative_groups.h>

namespace cg = cooperative_groups;

typedef unsigned short u16;
typedef __attribute__((ext_vector_type(8))) short bf16x8;
typedef __attribute__((ext_vector_type(8))) unsigned short u16x8;
typedef __attribute__((ext_vector_type(4))) unsigned short u16x4;
typedef __attribute__((ext_vector_type(4))) float f32x4;

#define DI static __device__ __forceinline__

// ---------------- workspace layout (bytes) ----------------
constexpr size_t OFF_WKQ  = 0;                               // 256x256 f32  (scale*Wk@Wq^T)
constexpr size_t OFF_WVW  = OFF_WKQ  + 256*256*4;            // 256x128 f32  (Wv@W3)
constexpr size_t OFF_WB   = OFF_WVW  + 256*128*4;            // 256 f32      (scale*Wk@bq)
constexpr size_t OFF_BYV  = OFF_WB   + 256*4;                // 128 f32      (b3 + bv@W3)
constexpr size_t OFF_BG   = OFF_BYV  + 128*4;                // 2048 f32     (bih+bhh)
constexpr size_t OFF_W2B  = OFF_BG   + 2048*4;               // 512x256 bf16
constexpr size_t OFF_W1F  = OFF_W2B  + 512*256*2;            // 16*4*64*8 bf16 (frag-swizzled W1)
constexpr size_t OFF_WIHF = OFF_W1F  + 16*4*64*8*2;          // 128*8*64*8 bf16
constexpr size_t OFF_WHHF = OFF_WIHF + 128*8*64*8*2;         // 128*16*64*8 bf16
constexpr size_t OFF_KT   = OFF_WHHF + 128*16*64*8*2;        // 64*1024*256 bf16
constexpr size_t OFF_VW   = OFF_KT   + (size_t)64*1024*256*2;// 64*1024*128 bf16
constexpr size_t OFF_S0   = OFF_VW   + (size_t)64*1024*128*2;// 65536 f32 (incl. mask bias)
constexpr size_t OFF_CB   = OFF_S0   + 65536*4;              // 64x512 f32 cell state
constexpr size_t OFF_HF   = OFF_CB   + 64*512*4;             // 64x512 f32 h
constexpr size_t OFF_HFR  = OFF_HF   + 64*512*4;             // 2 x (16*4*64*8) bf16 h frags (ping-pong)
constexpr size_t OFF_SC   = OFF_HFR  + 2*16*4*64*8*2;        // 64x1024 f32 raw scores
constexpr size_t OFF_PART = OFF_SC   + 64*1024*4;            // 64x4x130 f32 (m,S,ctx[128])

DI float bf2f(u16 u){ unsigned int v = ((unsigned int)u) << 16; return __uint_as_float(v); }
DI u16 f2bf(float f){ unsigned int u = __float_as_uint(f); unsigned int r = (u + 0x7FFFu + ((u>>16)&1u)) >> 16; return (u16)r; }
DI float sigm(float x){ return 1.f/(1.f + __expf(-x)); }
DI float tanh_(float x){ return 1.f - 2.f/(__expf(2.f*x) + 1.f); }

// frag slot for an A-operand element [row m][k]: lane=(m&15)|(((k>>3)&3)<<4), i=k&7, ktile=k>>5, mtile=m>>4
DI int fragIdx(int m, int k){ return (((k>>5)*4 + (m>>4))*64 + ((m&15) | (((k>>3)&3)<<4)))*8 + (k&7); }

// ---------------- one-time weight prep ----------------
__global__ __launch_bounds__(256) void kPrep(char* ws,
    const float* W1, const float* Wih, const float* Whh, const float* W2,
    const float* Wq, const float* bq, const float* Wk, const float* bk,
    const float* Wv, const float* bv, const float* W3, const float* b3,
    const float* bih, const float* bhh, const float* c0, const float* h0)
{
  const int wg = blockIdx.x, tid = threadIdx.x;
  if (wg < 64) {                       // Wkq[e][d] = scale * dot(Wk row e, Wq row d)
    float* Wkq = (float*)(ws + OFF_WKQ);
    for (int rr = 0; rr < 4; ++rr) {
      const int e = wg*4 + rr;
      float acc = 0.f;
      for (int d = 0; d < 256; ++d) acc = fmaf(Wk[e*256+d], Wq[tid*256+d], acc);
      Wkq[e*256 + tid] = acc * 0.0625f;
    }
  } else if (wg < 96) {                // Wvw[e][o] = dot(Wv row e, W3 col o)
    float* Wvw = (float*)(ws + OFF_WVW);
    if (tid < 128) {
      for (int rr = 0; rr < 8; ++rr) {
        const int e = (wg-64)*8 + rr;
        float acc = 0.f;
        for (int d = 0; d < 256; ++d) acc = fmaf(Wv[e*256+d], W3[d*128+tid], acc);
        Wvw[e*128 + tid] = acc;
      }
    }
  } else if (wg == 96) {               // wb, byv
    float* wb = (float*)(ws + OFF_WB);
    float acc = 0.f;
    for (int d = 0; d < 256; ++d) acc = fmaf(Wk[tid*256+d], bq[d], acc);
    wb[tid] = acc * 0.0625f;
    if (tid < 128) {
      float* byv = (float*)(ws + OFF_BYV);
      float a2 = b3[tid];
      for (int d = 0; d < 256; ++d) a2 = fmaf(bv[d], W3[d*128+tid], a2);
      byv[tid] = a2;
    }
  } else if (wg == 97) {               // bg = bih + bhh
    float* bg = (float*)(ws + OFF_BG);
    for (int j = tid; j < 2048; j += 256) bg[j] = bih[j] + bhh[j];
  } else if (wg < 106) {               // W2 -> bf16
    u16* W2b = (u16*)(ws + OFF_W2B);
    const int r0 = (wg - 98)*64;
    for (int rr = 0; rr < 64; ++rr) W2b[(r0+rr)*256 + tid] = f2bf(W2[(r0+rr)*256 + tid]);
  } else if (wg < 122) {               // W1 frag swizzle (B-operand): n natural order
    u16* W1f = (u16*)(ws + OFF_W1F);
    const int nt2 = wg - 106;
    for (int idx = tid; idx < 4*512; idx += 256) {
      const int kt2 = idx >> 9, rem = idx & 511, lane = rem >> 3, i = rem & 7;
      const int k = kt2*32 + (lane>>4)*8 + i, n = nt2*16 + (lane&15);
      W1f[((nt2*4+kt2)*64+lane)*8+i] = f2bf(W1[k*256+n]);
    }
  } else if (wg < 250) {               // Wih frag swizzle, gate-interleaved col permutation
    u16* Wihf = (u16*)(ws + OFF_WIHF);
    const int nt = wg - 122;
    for (int idx = tid; idx < 8*512; idx += 256) {
      const int kt = idx >> 9, rem = idx & 511, lane = rem >> 3, i = rem & 7;
      const int k = kt*32 + (lane>>4)*8 + i, r = lane & 15;
      const int gcol = (r>>2)*512 + nt*4 + (r&3);   // r: 0..3=i,4..7=f,8..11=g,12..15=o
      Wihf[((nt*8+kt)*64+lane)*8+i] = f2bf(Wih[k*2048 + gcol]);
    }
  } else if (wg < 378) {               // Whh frag swizzle
    u16* Whhf = (u16*)(ws + OFF_WHHF);
    const int nt = wg - 250;
    for (int idx = tid; idx < 16*512; idx += 256) {
      const int kt = idx >> 9, rem = idx & 511, lane = rem >> 3, i = rem & 7;
      const int k = kt*32 + (lane>>4)*8 + i, r = lane & 15;
      const int gcol = (r>>2)*512 + nt*4 + (r&3);
      Whhf[((nt*16+kt)*64+lane)*8+i] = f2bf(Whh[k*2048 + gcol]);
    }
  } else if (wg < 410) {               // state init: c0 -> cbuf, h0 -> hfrag[0]
    float* cb = (float*)(ws + OFF_CB);
    u16* hfr0 = (u16*)(ws + OFF_HFR);
    const int base = (wg - 378)*1024;
    for (int ii = tid; ii < 1024; ii += 256) {
      const int idx = base + ii, b = idx >> 9, j = idx & 511;
      cb[idx] = c0[idx];
      hfr0[fragIdx(b, j)] = f2bf(h0[idx]);
    }
  }
}

// ---------------- precompute kt, vw, s0 (mask bias folded in) ----------------
__global__ __launch_bounds__(256) void kKTVW(char* __restrict__ ws, const float* __restrict__ hid_r,
                                             const float* __restrict__ in_mask)
{
  const int wg = blockIdx.x, tid = threadIdx.x;
  __shared__ float lh[256*36];  // [e][r], padded to 36
  const float* Wkq = (const float*)(ws + OFF_WKQ);
  const float* Wvw = (const float*)(ws + OFF_WVW);
  const float* wb  = (const float*)(ws + OFF_WB);
  u16* kt = (u16*)(ws + OFF_KT);
  u16* vw = (u16*)(ws + OFF_VW);
  float* s0 = (float*)(ws + OFF_S0);
  const size_t r0 = (size_t)wg * 32;
  for (int idx = tid; idx < 32*256; idx += 256) {
    const int e = idx & 255, r = idx >> 8;
    lh[e*36 + r] = hid_r[(r0 + r)*256 + e];
  }
  __syncthreads();
  float acc[32];
  #pragma unroll
  for (int r = 0; r < 32; ++r) acc[r] = 0.f;
  for (int e = 0; e < 256; ++e) {
    const float wv = Wkq[e*256 + tid];
    #pragma unroll
    for (int r4 = 0; r4 < 8; ++r4) {
      const float4 l4 = *(const float4*)&lh[e*36 + r4*4];
      acc[r4*4+0] = fmaf(l4.x, wv, acc[r4*4+0]);
      acc[r4*4+1] = fmaf(l4.y, wv, acc[r4*4+1]);
      acc[r4*4+2] = fmaf(l4.z, wv, acc[r4*4+2]);
      acc[r4*4+3] = fmaf(l4.w, wv, acc[r4*4+3]);
    }
  }
  for (int r = 0; r < 32; ++r) kt[(r0 + r)*256 + tid] = f2bf(acc[r]);
  if (tid < 128) {
    #pragma unroll
    for (int r = 0; r < 32; ++r) acc[r] = 0.f;
    for (int e = 0; e < 256; ++e) {
      const float wv = Wvw[e*128 + tid];
      #pragma unroll
      for (int r4 = 0; r4 < 8; ++r4) {
        const float4 l4 = *(const float4*)&lh[e*36 + r4*4];
        acc[r4*4+0] = fmaf(l4.x, wv, acc[r4*4+0]);
        acc[r4*4+1] = fmaf(l4.y, wv, acc[r4*4+1]);
        acc[r4*4+2] = fmaf(l4.z, wv, acc[r4*4+2]);
        acc[r4*4+3] = fmaf(l4.w, wv, acc[r4*4+3]);
      }
    }
    for (int r = 0; r < 32; ++r) vw[(r0 + r)*128 + tid] = f2bf(acc[r]);
  } else if (tid < 160) {
    const int r = tid - 128;
    float a3 = 0.f;
    for (int e = 0; e < 256; ++e) a3 = fmaf(lh[e*36 + r], wb[e], a3);
    s0[r0 + r] = a3 + (in_mask[r0 + r] == 0.f ? -1e9f : 0.f);
  }
}

// ---------------- shared memory union for kMain ----------------
union Shm {
  struct {
    union {
      u16 yfrag[16*64*8];                                       // stages 1-2 (16 KB)
      struct { float gmerge[8*64*4]; float gtile[64*32]; } s3;  // stages 3-4 (16 KB)
    } u;
    union {
      u16 afrag[32*64*8];                                       // stages 2-3 (32 KB)
      float lfac[64*4];                                         // stage 1 only
    } v;
  } g;
  struct { float red[4*256]; float dxl[256]; float mrg[32*132]; } p2;  // ~22 KB
};

DI void writer(char* ws, const float* in_mask, float* dout, int b, int tid, int t)
{
  float* part = (float*)(ws + OFF_PART);
  float* scores = (float*)(ws + OFF_SC);
  float pm[4], pS[4], m = -1e30f;
  #pragma unroll
  for (int c = 0; c < 4; ++c) { pm[c] = part[(b*4+c)*130]; pS[c] = part[(b*4+c)*130+1]; m = fmaxf(m, pm[c]); }
  float Sv = 0.f;
  #pragma unroll
  for (int c = 0; c < 4; ++c) Sv += pS[c] * __expf(pm[c]-m);
  const float inv = 1.f / Sv;
  float* attn = dout + (size_t)64*1024*128;
  attn[((size_t)b*1024 + t)*1024 + tid] = __expf(scores[b*1024 + tid] - m) * inv;
  if (tid < 128) {
    const float* byv = (const float*)(ws + OFF_BYV);
    float a2 = 0.f;
    #pragma unroll
    for (int c = 0; c < 4; ++c) a2 += __expf(pm[c]-m) * part[(b*4+c)*130+2+tid];
    const float y = fmaxf(a2*inv + byv[tid], 0.f);
    dout[((size_t)b*1024 + t)*128 + tid] = y * in_mask[b*1024 + t];
  }
}

// ---------------- persistent cooperative kernel: whole scan ----------------
__global__ __launch_bounds__(1024) void kMain(char* __restrict__ ws, const float* __restrict__ init_in,
    const float* __restrict__ in_mask, const float* __restrict__ b1, const float* __restrict__ b2,
    float* __restrict__ dout)
{
  cg::grid_group grid = cg::this_grid();
  const int wg = blockIdx.x, tid = threadIdx.x;
  __shared__ Shm shm;

  float* part = (float*)(ws + OFF_PART);
  const float* byv = (const float*)(ws + OFF_BYV);

  for (int s = 0; s < 1024; ++s) {
    // ================= PHASE 1 =================
    if (wg < 64) {
      // ---- gates WG: owns h columns j = wg*8 .. wg*8+7 ----
      // stage 1: y -> yfrag
      if (s == 0) {
        for (int idx = tid; idx < 64*128; idx += 1024) {
          const int b = idx >> 7, d0 = idx & 127;
          shm.g.u.yfrag[fragIdx(b, d0)] = f2bf(init_in[b*128 + d0]);
        }
      } else {
        if (tid < 64) {
          const int b = tid;
          float pm[4], m = -1e30f;
          #pragma unroll
          for (int c = 0; c < 4; ++c) { pm[c] = part[(b*4+c)*130]; m = fmaxf(m, pm[c]); }
          float Sv = 0.f, pf[4];
          #pragma unroll
          for (int c = 0; c < 4; ++c) { pf[c] = __expf(pm[c]-m); Sv += part[(b*4+c)*130+1]*pf[c]; }
          const float inv = 1.f/Sv;
          #pragma unroll
          for (int c = 0; c < 4; ++c) shm.g.v.lfac[b*4+c] = pf[c]*inv;
        }
        __syncthreads();
        for (int idx = tid; idx < 64*128; idx += 1024) {
          const int b = idx >> 7, d0 = idx & 127;
          float a2 = byv[d0];
          #pragma unroll
          for (int c = 0; c < 4; ++c) a2 += shm.g.v.lfac[b*4+c]*part[(b*4+c)*130+2+d0];
          shm.g.u.yfrag[fragIdx(b, d0)] = f2bf(fmaxf(a2, 0.f));
        }
      }
      __syncthreads();
      const int w = tid >> 6, lane = tid & 63;
      // stage 2: a = relu(y@W1 + b1); 16 waves cover 64 (mt,nt2) tiles
      {
        const u16* W1f = (const u16*)(ws + OFF_W1F);
        const int mt = w & 3, nb0 = w >> 2;
        for (int k = 0; k < 4; ++k) {
          const int nt2 = nb0 + k*4;
          f32x4 acc = {0.f,0.f,0.f,0.f};
          #pragma unroll
          for (int kt2 = 0; kt2 < 4; ++kt2) {
            bf16x8 av = *(const bf16x8*)&shm.g.u.yfrag[((kt2*4+mt)*64+lane)*8];
            bf16x8 bv = *(const bf16x8*)&W1f[((nt2*4+kt2)*64+lane)*8];
            acc = __builtin_amdgcn_mfma_f32_16x16x32_bf16(av, bv, acc, 0, 0, 0);
          }
          const int col = nt2*16 + (lane&15);
          const float bb = b1[col];
          #pragma unroll
          for (int i = 0; i < 4; ++i) {
            const int b = mt*16 + (lane>>4)*4 + i;
            shm.g.v.afrag[fragIdx(b, col)] = f2bf(fmaxf(acc[i] + bb, 0.f));
          }
        }
      }
      __syncthreads();
      // stage 3: gates 64x32 tile = a@Wih + h@Whh + bg; 16 waves: (mt, ntile, khalf)
      {
        const u16* Wihf = (const u16*)(ws + OFF_WIHF);
        const u16* Whhf = (const u16*)(ws + OFF_WHHF);
        const u16* hfr = (const u16*)(ws + OFF_HFR) + (size_t)(s & 1)*(16*4*64*8);
        const int mt = w & 3, ntile = (w>>2) & 1, khalf = w >> 3;
        const int nt = wg*2 + ntile;
        f32x4 acc = {0.f,0.f,0.f,0.f};
        if (khalf == 0) {
          for (int kt = 0; kt < 8; ++kt) {
            bf16x8 av = *(const bf16x8*)&shm.g.v.afrag[((kt*4+mt)*64+lane)*8];
            bf16x8 bv = *(const bf16x8*)&Wihf[((nt*8+kt)*64+lane)*8];
            acc = __builtin_amdgcn_mfma_f32_16x16x32_bf16(av, bv, acc, 0, 0, 0);
          }
          for (int kt = 0; kt < 4; ++kt) {
            bf16x8 av = *(const bf16x8*)&hfr[((kt*4+mt)*64+lane)*8];
            bf16x8 bv = *(const bf16x8*)&Whhf[((nt*16+kt)*64+lane)*8];
            acc = __builtin_amdgcn_mfma_f32_16x16x32_bf16(av, bv, acc, 0, 0, 0);
          }
        } else {
          for (int kt = 4; kt < 16; ++kt) {
            bf16x8 av = *(const bf16x8*)&hfr[((kt*4+mt)*64+lane)*8];
            bf16x8 bv = *(const bf16x8*)&Whhf[((nt*16+kt)*64+lane)*8];
            acc = __builtin_amdgcn_mfma_f32_16x16x32_bf16(av, bv, acc, 0, 0, 0);
          }
        }
        __syncthreads();   // afrag reads done; s3 region (aliases yfrag) now writable
        if (khalf == 1) {
          #pragma unroll
          for (int i = 0; i < 4; ++i) shm.g.u.s3.gmerge[((ntile*4+mt)*64+lane)*4+i] = acc[i];
        }
        __syncthreads();
        if (khalf == 0) {
          const float* bg = (const float*)(ws + OFF_BG);
          const int r = lane & 15;
          const float bb = bg[(r>>2)*512 + nt*4 + (r&3)];
          #pragma unroll
          for (int i = 0; i < 4; ++i) {
            const int b = mt*16 + (lane>>4)*4 + i;
            shm.g.u.s3.gtile[b*32 + ntile*16 + r] = acc[i] + shm.g.u.s3.gmerge[((ntile*4+mt)*64+lane)*4+i] + bb;
          }
        }
      }
      __syncthreads();
      // stage 4: h,c pointwise for this WG's 8 j columns
      if (tid < 512) {
        const int b = tid >> 3, jj = tid & 7;
        const int j = wg*8 + jj;
        const int cb32 = b*32 + (jj>>2)*16 + (jj&3);
        const float ig = shm.g.u.s3.gtile[cb32 + 0];
        const float fg = shm.g.u.s3.gtile[cb32 + 4];
        const float gg = shm.g.u.s3.gtile[cb32 + 8];
        const float og = shm.g.u.s3.gtile[cb32 + 12];
        float* cb = (float*)(ws + OFF_CB);
        float* hf = (float*)(ws + OFF_HF);
        u16* hfw = (u16*)(ws + OFF_HFR) + (size_t)((s & 1) ^ 1)*(16*4*64*8);
        const float cold = cb[b*512 + j];
        const float cnew = sigm(fg)*cold + sigm(ig)*tanh_(gg);
        const float hnew = sigm(og)*tanh_(cnew);
        cb[b*512 + j] = cnew;
        hf[b*512 + j] = hnew;
        hfw[fragIdx(b, j)] = f2bf(hnew);
      }
    } else if (wg < 128) {
      if (s > 0) writer(ws, in_mask, dout, wg - 64, tid, s - 1);
    }
    __threadfence();
    grid.sync();

    // ================= PHASE 2: dx + flash attention chunk =================
    {
      const int b = wg >> 2, ch = wg & 3;
      const float* hf = (const float*)(ws + OFF_HF);
      const u16* W2b = (const u16*)(ws + OFF_W2B);
      {  // dx = relu(h[b]@W2 + b2), redundant per chunk-WG
        const int n = tid & 255, q = tid >> 8;
        const float* hb = hf + b*512;
        float acc = 0.f;
        #pragma unroll 4
        for (int k = q*128; k < q*128 + 128; ++k)
          acc = fmaf(hb[k], bf2f(W2b[k*256 + n]), acc);
        shm.p2.red[q*256 + n] = acc;
      }
      __syncthreads();
      if (tid < 256) shm.p2.dxl[tid] = fmaxf(shm.p2.red[tid] + shm.p2.red[256+tid] + shm.p2.red[512+tid] + shm.p2.red[768+tid] + b2[tid], 0.f);
      __syncthreads();

      const int hl = tid & 31;
      const int unit = tid >> 5;
      float dxv[8];
      #pragma unroll
      for (int j2 = 0; j2 < 8; ++j2) dxv[j2] = shm.p2.dxl[hl*8 + j2];
      const u16* kt = (const u16*)(ws + OFF_KT);
      const u16* vw = (const u16*)(ws + OFF_VW);
      const float* s0 = (const float*)(ws + OFF_S0);
      float m = -1e30f, S = 0.f, cx0 = 0.f, cx1 = 0.f, cx2 = 0.f, cx3 = 0.f, keep = 0.f;
      for (int i = 0; i < 8; ++i) {
        const int l = ch*256 + i*32 + unit;
        const size_t row = (size_t)b*1024 + l;
        const u16x8 kv = *(const u16x8*)(kt + row*256 + hl*8);
        float sum = 0.f;
        #pragma unroll
        for (int j2 = 0; j2 < 8; ++j2) sum = fmaf(bf2f(kv[j2]), dxv[j2], sum);
        #pragma unroll
        for (int d = 1; d < 32; d <<= 1) sum += __shfl_xor(sum, d, 64);
        const float sc = sum + s0[row];
        if (hl == i) keep = sc;
        const float mn = fmaxf(m, sc);
        const float cf = __expf(m - mn);
        const float e  = __expf(sc - mn);
        S = S*cf + e;
        cx0 *= cf; cx1 *= cf; cx2 *= cf; cx3 *= cf;
        m = mn;
        const u16x4 vv = *(const u16x4*)(vw + row*128 + hl*4);
        cx0 = fmaf(e, bf2f(vv[0]), cx0);
        cx1 = fmaf(e, bf2f(vv[1]), cx1);
        cx2 = fmaf(e, bf2f(vv[2]), cx2);
        cx3 = fmaf(e, bf2f(vv[3]), cx3);
      }
      if (hl < 8) ((float*)(ws + OFF_SC))[b*1024 + ch*256 + hl*32 + unit] = keep;
      shm.p2.mrg[unit*132 + 4 + hl*4 + 0] = cx0;
      shm.p2.mrg[unit*132 + 4 + hl*4 + 1] = cx1;
      shm.p2.mrg[unit*132 + 4 + hl*4 + 2] = cx2;
      shm.p2.mrg[unit*132 + 4 + hl*4 + 3] = cx3;
      if (hl == 0) { shm.p2.mrg[unit*132] = m; shm.p2.mrg[unit*132+1] = S; }
      __syncthreads();
      if (tid < 128) {
        float mg = -1e30f;
        for (int u = 0; u < 32; ++u) mg = fmaxf(mg, shm.p2.mrg[u*132]);
        float Sg = 0.f, cx = 0.f;
        for (int u = 0; u < 32; ++u) {
          const float f = __expf(shm.p2.mrg[u*132] - mg);
          Sg = fmaf(shm.p2.mrg[u*132+1], f, Sg);
          cx = fmaf(f, shm.p2.mrg[u*132 + 4 + tid], cx);
        }
        part[(b*4+ch)*130 + 2 + tid] = cx;
        if (tid == 0) { part[(b*4+ch)*130] = mg; part[(b*4+ch)*130+1] = Sg; }
      }
    }
    __threadfence();
    grid.sync();
  }
  // epilogue: write step 1023 outputs
  if (wg >= 64 && wg < 128) writer(ws, in_mask, dout, wg - 64, tid, 1023);
}

extern "C" void kernel_launch(void* const* d_in, const int* in_sizes, int n_in,
                              void* d_out, int out_size, void* d_ws, size_t ws_size,
                              hipStream_t stream)
{
  (void)in_sizes; (void)n_in; (void)out_size; (void)ws_size;
  const float* hid_r  = (const float*)d_in[0];
  const float* in_mask= (const float*)d_in[1];
  const float* init_in= (const float*)d_in[2];
  const float* h0     = (const float*)d_in[3];
  const float* c0     = (const float*)d_in[4];
  const float* W1     = (const float*)d_in[5];
  const float* b1     = (const float*)d_in[6];
  const float* Wih    = (const float*)d_in[7];
  const float* Whh    = (const float*)d_in[8];
  const float* bih    = (const float*)d_in[9];
  const float* bhh    = (const float*)d_in[10];
  const float* W2     = (const float*)d_in[11];
  const float* b2     = (const float*)d_in[12];
  const float* Wq     = (const float*)d_in[13];
  const float* bq     = (const float*)d_in[14];
  const float* Wk     = (const float*)d_in[15];
  const float* bk     = (const float*)d_in[16];
  const float* Wv     = (const float*)d_in[17];
  const float* bv     = (const float*)d_in[18];
  const float* W3     = (const float*)d_in[19];
  const float* b3     = (const float*)d_in[20];
  char* ws = (char*)d_ws;
  float* out = (float*)d_out;

  hipLaunchKernelGGL(kPrep, dim3(410), dim3(256), 0, stream, ws,
                     W1, Wih, Whh, W2, Wq, bq, Wk, bk, Wv, bv, W3, b3, bih, bhh, c0, h0);
  hipLaunchKernelGGL(kKTVW, dim3(2048), dim3(256), 0, stream, ws, hid_r, in_mask);

  void* args[] = {(void*)&ws, (void*)&init_in, (void*)&in_mask, (void*)&b1, (void*)&b2, (void*)&out};
  hipLaunchCooperativeKernel((void*)kMain, dim3(256), dim3(1024), args, 0, stream);
}

// Round 3
// 86647.723 us; speedup vs baseline: 3.0273x; 3.0273x over previous
//
#include <hip/hip_runtime.h>

typedef unsigned short u16;
typedef unsigned int u32;
typedef unsigned long long u64;
typedef __attribute__((ext_vector_type(8))) short bf16x8;
typedef __attribute__((ext_vector_type(8))) unsigned short u16x8;
typedef __attribute__((ext_vector_type(4))) unsigned short u16x4;
typedef __attribute__((ext_vector_type(4))) float f32x4;

#define DI static __device__ __forceinline__

// ---------------- workspace layout (bytes) ----------------
constexpr size_t OFF_WKQ  = 0;                               // 256x256 f32  (scale*Wk@Wq^T)
constexpr size_t OFF_WVW  = OFF_WKQ  + 256*256*4;            // 256x128 f32  (Wv@W3)
constexpr size_t OFF_WB   = OFF_WVW  + 256*128*4;            // 256 f32      (scale*Wk@bq)
constexpr size_t OFF_BYV  = OFF_WB   + 256*4;                // 128 f32      (b3 + bv@W3)
constexpr size_t OFF_BG   = OFF_BYV  + 128*4;                // 2048 f32     (bih+bhh)
constexpr size_t OFF_W2B  = OFF_BG   + 2048*4;               // 512x256 bf16
constexpr size_t OFF_W1F  = OFF_W2B  + 512*256*2;            // 16*4*64*8 bf16 (frag-swizzled W1)
constexpr size_t OFF_WIHF = OFF_W1F  + 16*4*64*8*2;          // 128*8*64*8 bf16
constexpr size_t OFF_WHHF = OFF_WIHF + 128*8*64*8*2;         // 128*16*64*8 bf16
constexpr size_t OFF_KT   = OFF_WHHF + 128*16*64*8*2;        // 64*1024*256 bf16
constexpr size_t OFF_VW   = OFF_KT   + (size_t)64*1024*256*2;// 64*1024*128 bf16
constexpr size_t OFF_S0   = OFF_VW   + (size_t)64*1024*128*2;// 65536 f32 (incl. mask bias)
constexpr size_t OFF_CB   = OFF_S0   + 65536*4;              // 64x512 f32 cell state (WG-private)
constexpr size_t OFF_HF   = OFF_CB   + 64*512*4;             // 64x512 f32 h          (cross-WG, bypass)
constexpr size_t OFF_HFR  = OFF_HF   + 64*512*4;             // 2 x (16*4*64*8) bf16  (cross-WG, bypass)
constexpr size_t OFF_SC   = OFF_HFR  + 2*16*4*64*8*2;        // 64x1024 f32 raw scores(cross-WG, bypass)
constexpr size_t OFF_PART = OFF_SC   + 64*1024*4;            // 64x4x130 f32          (cross-WG, bypass)
constexpr size_t OFF_CNT  = OFF_PART + 64*4*130*4;           // 1 u32 barrier counter (64B-aligned)

DI float bf2f(u16 u){ unsigned int v = ((unsigned int)u) << 16; return __uint_as_float(v); }
DI u16 f2bf(float f){ unsigned int u = __float_as_uint(f); unsigned int r = (u + 0x7FFFu + ((u>>16)&1u)) >> 16; return (u16)r; }
DI float sigm(float x){ return 1.f/(1.f + __expf(-x)); }
DI float tanh_(float x){ return 1.f - 2.f/(__expf(2.f*x) + 1.f); }

// ---- L2-bypassing (agent-scope, relaxed) accessors for cross-WG data ----
DI float aldf(const float* p){ return __hip_atomic_load(p, __ATOMIC_RELAXED, __HIP_MEMORY_SCOPE_AGENT); }
DI void  astf(float* p, float v){ __hip_atomic_store(p, v, __ATOMIC_RELAXED, __HIP_MEMORY_SCOPE_AGENT); }
DI void  astu32(u32* p, u32 v){ __hip_atomic_store(p, v, __ATOMIC_RELAXED, __HIP_MEMORY_SCOPE_AGENT); }
DI void  astu64(u64* p, u64 v){ __hip_atomic_store(p, v, __ATOMIC_RELAXED, __HIP_MEMORY_SCOPE_AGENT); }
DI u64   aldu64(const u64* p){ return __hip_atomic_load(p, __ATOMIC_RELAXED, __HIP_MEMORY_SCOPE_AGENT); }

union FragU { u64 u[2]; bf16x8 v; };
DI bf16x8 ald_frag(const u16* p){
  FragU r; const u64* q = (const u64*)p;
  r.u[0] = aldu64(q); r.u[1] = aldu64(q+1);
  return r.v;
}

// frag slot for an A-operand element [row m][k]: lane=(m&15)|(((k>>3)&3)<<4), i=k&7, ktile=k>>5, mtile=m>>4
DI int fragIdx(int m, int k){ return (((k>>5)*4 + (m>>4))*64 + ((m&15) | (((k>>3)&3)<<4)))*8 + (k&7); }

// ---- hand-rolled grid barrier: monotonic epoch counter, thread0-only, no cache maintenance ----
DI void gbar(char* ws, unsigned target){
  __syncthreads();   // compiler drains vmcnt before s_barrier -> all waves' sc1 stores visible at MALL
  if (threadIdx.x == 0) {
    unsigned* cnt = (unsigned*)(ws + OFF_CNT);
    __hip_atomic_fetch_add(cnt, 1u, __ATOMIC_RELAXED, __HIP_MEMORY_SCOPE_AGENT);
    while (__hip_atomic_load(cnt, __ATOMIC_RELAXED, __HIP_MEMORY_SCOPE_AGENT) < target)
      __builtin_amdgcn_s_sleep(1);
  }
  __syncthreads();
}

// ---------------- one-time weight prep ----------------
__global__ __launch_bounds__(256) void kPrep(char* ws,
    const float* W1, const float* Wih, const float* Whh, const float* W2,
    const float* Wq, const float* bq, const float* Wk, const float* bk,
    const float* Wv, const float* bv, const float* W3, const float* b3,
    const float* bih, const float* bhh, const float* c0, const float* h0)
{
  const int wg = blockIdx.x, tid = threadIdx.x;
  if (wg < 64) {                       // Wkq[e][d] = scale * dot(Wk row e, Wq row d)
    float* Wkq = (float*)(ws + OFF_WKQ);
    for (int rr = 0; rr < 4; ++rr) {
      const int e = wg*4 + rr;
      float acc = 0.f;
      for (int d = 0; d < 256; ++d) acc = fmaf(Wk[e*256+d], Wq[tid*256+d], acc);
      Wkq[e*256 + tid] = acc * 0.0625f;
    }
  } else if (wg < 96) {                // Wvw[e][o] = dot(Wv row e, W3 col o)
    float* Wvw = (float*)(ws + OFF_WVW);
    if (tid < 128) {
      for (int rr = 0; rr < 8; ++rr) {
        const int e = (wg-64)*8 + rr;
        float acc = 0.f;
        for (int d = 0; d < 256; ++d) acc = fmaf(Wv[e*256+d], W3[d*128+tid], acc);
        Wvw[e*128 + tid] = acc;
      }
    }
  } else if (wg == 96) {               // wb, byv
    float* wb = (float*)(ws + OFF_WB);
    float acc = 0.f;
    for (int d = 0; d < 256; ++d) acc = fmaf(Wk[tid*256+d], bq[d], acc);
    wb[tid] = acc * 0.0625f;
    if (tid < 128) {
      float* byv = (float*)(ws + OFF_BYV);
      float a2 = b3[tid];
      for (int d = 0; d < 256; ++d) a2 = fmaf(bv[d], W3[d*128+tid], a2);
      byv[tid] = a2;
    }
  } else if (wg == 97) {               // bg = bih + bhh; zero barrier counter (replay determinism)
    float* bg = (float*)(ws + OFF_BG);
    for (int j = tid; j < 2048; j += 256) bg[j] = bih[j] + bhh[j];
    if (tid == 0) *(unsigned*)(ws + OFF_CNT) = 0u;
  } else if (wg < 106) {               // W2 -> bf16
    u16* W2b = (u16*)(ws + OFF_W2B);
    const int r0 = (wg - 98)*64;
    for (int rr = 0; rr < 64; ++rr) W2b[(r0+rr)*256 + tid] = f2bf(W2[(r0+rr)*256 + tid]);
  } else if (wg < 122) {               // W1 frag swizzle (B-operand)
    u16* W1f = (u16*)(ws + OFF_W1F);
    const int nt2 = wg - 106;
    for (int idx = tid; idx < 4*512; idx += 256) {
      const int kt2 = idx >> 9, rem = idx & 511, lane = rem >> 3, i = rem & 7;
      const int k = kt2*32 + (lane>>4)*8 + i, n = nt2*16 + (lane&15);
      W1f[((nt2*4+kt2)*64+lane)*8+i] = f2bf(W1[k*256+n]);
    }
  } else if (wg < 250) {               // Wih frag swizzle, gate-interleaved col permutation
    u16* Wihf = (u16*)(ws + OFF_WIHF);
    const int nt = wg - 122;
    for (int idx = tid; idx < 8*512; idx += 256) {
      const int kt = idx >> 9, rem = idx & 511, lane = rem >> 3, i = rem & 7;
      const int k = kt*32 + (lane>>4)*8 + i, r = lane & 15;
      const int gcol = (r>>2)*512 + nt*4 + (r&3);   // r: 0..3=i,4..7=f,8..11=g,12..15=o
      Wihf[((nt*8+kt)*64+lane)*8+i] = f2bf(Wih[k*2048 + gcol]);
    }
  } else if (wg < 378) {               // Whh frag swizzle
    u16* Whhf = (u16*)(ws + OFF_WHHF);
    const int nt = wg - 250;
    for (int idx = tid; idx < 16*512; idx += 256) {
      const int kt = idx >> 9, rem = idx & 511, lane = rem >> 3, i = rem & 7;
      const int k = kt*32 + (lane>>4)*8 + i, r = lane & 15;
      const int gcol = (r>>2)*512 + nt*4 + (r&3);
      Whhf[((nt*16+kt)*64+lane)*8+i] = f2bf(Whh[k*2048 + gcol]);
    }
  } else if (wg < 410) {               // state init: c0 -> cbuf, h0 -> hfrag[0]
    float* cb = (float*)(ws + OFF_CB);
    u16* hfr0 = (u16*)(ws + OFF_HFR);
    const int base = (wg - 378)*1024;
    for (int ii = tid; ii < 1024; ii += 256) {
      const int idx = base + ii, b = idx >> 9, j = idx & 511;
      cb[idx] = c0[idx];
      hfr0[fragIdx(b, j)] = f2bf(h0[idx]);
    }
  }
}

// ---------------- precompute kt, vw, s0 (mask bias folded in) ----------------
__global__ __launch_bounds__(256) void kKTVW(char* __restrict__ ws, const float* __restrict__ hid_r,
                                             const float* __restrict__ in_mask)
{
  const int wg = blockIdx.x, tid = threadIdx.x;
  __shared__ float lh[256*36];  // [e][r], padded to 36
  const float* Wkq = (const float*)(ws + OFF_WKQ);
  const float* Wvw = (const float*)(ws + OFF_WVW);
  const float* wb  = (const float*)(ws + OFF_WB);
  u16* kt = (u16*)(ws + OFF_KT);
  u16* vw = (u16*)(ws + OFF_VW);
  float* s0 = (float*)(ws + OFF_S0);
  const size_t r0 = (size_t)wg * 32;
  for (int idx = tid; idx < 32*256; idx += 256) {
    const int e = idx & 255, r = idx >> 8;
    lh[e*36 + r] = hid_r[(r0 + r)*256 + e];
  }
  __syncthreads();
  float acc[32];
  #pragma unroll
  for (int r = 0; r < 32; ++r) acc[r] = 0.f;
  for (int e = 0; e < 256; ++e) {
    const float wv = Wkq[e*256 + tid];
    #pragma unroll
    for (int r4 = 0; r4 < 8; ++r4) {
      const float4 l4 = *(const float4*)&lh[e*36 + r4*4];
      acc[r4*4+0] = fmaf(l4.x, wv, acc[r4*4+0]);
      acc[r4*4+1] = fmaf(l4.y, wv, acc[r4*4+1]);
      acc[r4*4+2] = fmaf(l4.z, wv, acc[r4*4+2]);
      acc[r4*4+3] = fmaf(l4.w, wv, acc[r4*4+3]);
    }
  }
  for (int r = 0; r < 32; ++r) kt[(r0 + r)*256 + tid] = f2bf(acc[r]);
  if (tid < 128) {
    #pragma unroll
    for (int r = 0; r < 32; ++r) acc[r] = 0.f;
    for (int e = 0; e < 256; ++e) {
      const float wv = Wvw[e*128 + tid];
      #pragma unroll
      for (int r4 = 0; r4 < 8; ++r4) {
        const float4 l4 = *(const float4*)&lh[e*36 + r4*4];
        acc[r4*4+0] = fmaf(l4.x, wv, acc[r4*4+0]);
        acc[r4*4+1] = fmaf(l4.y, wv, acc[r4*4+1]);
        acc[r4*4+2] = fmaf(l4.z, wv, acc[r4*4+2]);
        acc[r4*4+3] = fmaf(l4.w, wv, acc[r4*4+3]);
      }
    }
    for (int r = 0; r < 32; ++r) vw[(r0 + r)*128 + tid] = f2bf(acc[r]);
  } else if (tid < 160) {
    const int r = tid - 128;
    float a3 = 0.f;
    for (int e = 0; e < 256; ++e) a3 = fmaf(lh[e*36 + r], wb[e], a3);
    s0[r0 + r] = a3 + (in_mask[r0 + r] == 0.f ? -1e9f : 0.f);
  }
}

// ---------------- shared memory union for kMain ----------------
union Shm {
  struct {
    union {
      u16 yfrag[16*64*8];                                       // stages 1-2 (16 KB)
      struct { float gmerge[8*64*4]; float gtile[64*32]; } s3;  // stages 3-4 (16 KB)
    } u;
    union {
      u16 afrag[32*64*8];                                       // stages 2-3 (32 KB)
      float lfac[64*4];                                         // stage 1 only
    } v;
  } g;
  struct { float red[4*256]; float dxl[256]; float hstage[512]; float mrg[32*132]; } p2;
};

DI void writer(char* ws, const float* in_mask, float* dout, int b, int tid, int t)
{
  float* part = (float*)(ws + OFF_PART);
  float* scores = (float*)(ws + OFF_SC);
  float pm[4], pS[4], m = -1e30f;
  #pragma unroll
  for (int c = 0; c < 4; ++c) { pm[c] = aldf(&part[(b*4+c)*130]); pS[c] = aldf(&part[(b*4+c)*130+1]); m = fmaxf(m, pm[c]); }
  float Sv = 0.f;
  #pragma unroll
  for (int c = 0; c < 4; ++c) Sv += pS[c] * __expf(pm[c]-m);
  const float inv = 1.f / Sv;
  float* attn = dout + (size_t)64*1024*128;
  attn[((size_t)b*1024 + t)*1024 + tid] = __expf(aldf(&scores[b*1024 + tid]) - m) * inv;
  if (tid < 128) {
    const float* byv = (const float*)(ws + OFF_BYV);
    float a2 = 0.f;
    #pragma unroll
    for (int c = 0; c < 4; ++c) a2 += __expf(pm[c]-m) * aldf(&part[(b*4+c)*130+2+tid]);
    const float y = fmaxf(a2*inv + byv[tid], 0.f);
    dout[((size_t)b*1024 + t)*128 + tid] = y * in_mask[b*1024 + t];
  }
}

// ---------------- persistent kernel: whole scan, custom barrier ----------------
__global__ __launch_bounds__(1024) void kMain(char* __restrict__ ws, const float* __restrict__ init_in,
    const float* __restrict__ in_mask, const float* __restrict__ b1, const float* __restrict__ b2,
    float* __restrict__ dout)
{
  const int wg = blockIdx.x, tid = threadIdx.x;
  __shared__ Shm shm;

  float* part = (float*)(ws + OFF_PART);
  const float* byv = (const float*)(ws + OFF_BYV);
  unsigned bt = 0;

  for (int s = 0; s < 1024; ++s) {
    // ================= PHASE 1 =================
    if (wg < 64) {
      // ---- gates WG: owns h columns j = wg*8 .. wg*8+7 ----
      // stage 1: y -> yfrag
      if (s == 0) {
        for (int idx = tid; idx < 64*128; idx += 1024) {
          const int b = idx >> 7, d0 = idx & 127;
          shm.g.u.yfrag[fragIdx(b, d0)] = f2bf(init_in[b*128 + d0]);
        }
      } else {
        if (tid < 64) {
          const int b = tid;
          float pm[4], m = -1e30f;
          #pragma unroll
          for (int c = 0; c < 4; ++c) { pm[c] = aldf(&part[(b*4+c)*130]); m = fmaxf(m, pm[c]); }
          float Sv = 0.f, pf[4];
          #pragma unroll
          for (int c = 0; c < 4; ++c) { pf[c] = __expf(pm[c]-m); Sv += aldf(&part[(b*4+c)*130+1])*pf[c]; }
          const float inv = 1.f/Sv;
          #pragma unroll
          for (int c = 0; c < 4; ++c) shm.g.v.lfac[b*4+c] = pf[c]*inv;
        }
        __syncthreads();
        for (int idx = tid; idx < 64*128; idx += 1024) {
          const int b = idx >> 7, d0 = idx & 127;
          float a2 = byv[d0];
          #pragma unroll
          for (int c = 0; c < 4; ++c) a2 += shm.g.v.lfac[b*4+c]*aldf(&part[(b*4+c)*130+2+d0]);
          shm.g.u.yfrag[fragIdx(b, d0)] = f2bf(fmaxf(a2, 0.f));
        }
      }
      __syncthreads();
      const int w = tid >> 6, lane = tid & 63;
      // stage 2: a = relu(y@W1 + b1); 16 waves cover 64 (mt,nt2) tiles
      {
        const u16* W1f = (const u16*)(ws + OFF_W1F);
        const int mt = w & 3, nb0 = w >> 2;
        for (int k = 0; k < 4; ++k) {
          const int nt2 = nb0 + k*4;
          f32x4 acc = {0.f,0.f,0.f,0.f};
          #pragma unroll
          for (int kt2 = 0; kt2 < 4; ++kt2) {
            bf16x8 av = *(const bf16x8*)&shm.g.u.yfrag[((kt2*4+mt)*64+lane)*8];
            bf16x8 bv = *(const bf16x8*)&W1f[((nt2*4+kt2)*64+lane)*8];
            acc = __builtin_amdgcn_mfma_f32_16x16x32_bf16(av, bv, acc, 0, 0, 0);
          }
          const int col = nt2*16 + (lane&15);
          const float bb = b1[col];
          #pragma unroll
          for (int i = 0; i < 4; ++i) {
            const int b = mt*16 + (lane>>4)*4 + i;
            shm.g.v.afrag[fragIdx(b, col)] = f2bf(fmaxf(acc[i] + bb, 0.f));
          }
        }
      }
      __syncthreads();
      // stage 3: gates 64x32 tile = a@Wih + h@Whh + bg; 16 waves: (mt, ntile, khalf)
      {
        const u16* Wihf = (const u16*)(ws + OFF_WIHF);
        const u16* Whhf = (const u16*)(ws + OFF_WHHF);
        const u16* hfr = (const u16*)(ws + OFF_HFR) + (size_t)(s & 1)*(16*4*64*8);
        const int mt = w & 3, ntile = (w>>2) & 1, khalf = w >> 3;
        const int nt = wg*2 + ntile;
        f32x4 acc = {0.f,0.f,0.f,0.f};
        if (khalf == 0) {
          for (int kt = 0; kt < 8; ++kt) {
            bf16x8 av = *(const bf16x8*)&shm.g.v.afrag[((kt*4+mt)*64+lane)*8];
            bf16x8 bv = *(const bf16x8*)&Wihf[((nt*8+kt)*64+lane)*8];
            acc = __builtin_amdgcn_mfma_f32_16x16x32_bf16(av, bv, acc, 0, 0, 0);
          }
          for (int kt = 0; kt < 4; ++kt) {
            bf16x8 av = ald_frag(&hfr[((kt*4+mt)*64+lane)*8]);
            bf16x8 bv = *(const bf16x8*)&Whhf[((nt*16+kt)*64+lane)*8];
            acc = __builtin_amdgcn_mfma_f32_16x16x32_bf16(av, bv, acc, 0, 0, 0);
          }
        } else {
          for (int kt = 4; kt < 16; ++kt) {
            bf16x8 av = ald_frag(&hfr[((kt*4+mt)*64+lane)*8]);
            bf16x8 bv = *(const bf16x8*)&Whhf[((nt*16+kt)*64+lane)*8];
            acc = __builtin_amdgcn_mfma_f32_16x16x32_bf16(av, bv, acc, 0, 0, 0);
          }
        }
        __syncthreads();   // afrag reads done; s3 region (aliases yfrag) now writable
        if (khalf == 1) {
          #pragma unroll
          for (int i = 0; i < 4; ++i) shm.g.u.s3.gmerge[((ntile*4+mt)*64+lane)*4+i] = acc[i];
        }
        __syncthreads();
        if (khalf == 0) {
          const float* bg = (const float*)(ws + OFF_BG);
          const int r = lane & 15;
          const float bb = bg[(r>>2)*512 + nt*4 + (r&3)];
          #pragma unroll
          for (int i = 0; i < 4; ++i) {
            const int b = mt*16 + (lane>>4)*4 + i;
            shm.g.u.s3.gtile[b*32 + ntile*16 + r] = acc[i] + shm.g.u.s3.gmerge[((ntile*4+mt)*64+lane)*4+i] + bb;
          }
        }
      }
      __syncthreads();
      // stage 4: h,c pointwise; 256 threads x 2 cols -> packed bypass stores
      if (tid < 256) {
        const int b = tid >> 2, jj2 = tid & 3;
        float* cb = (float*)(ws + OFF_CB);
        float* hf = (float*)(ws + OFF_HF);
        u16* hfw = (u16*)(ws + OFF_HFR) + (size_t)((s & 1) ^ 1)*(16*4*64*8);
        float hv[2];
        #pragma unroll
        for (int t2 = 0; t2 < 2; ++t2) {
          const int jj = jj2*2 + t2;
          const int j = wg*8 + jj;
          const int cb32 = b*32 + (jj>>2)*16 + (jj&3);
          const float ig = shm.g.u.s3.gtile[cb32 + 0];
          const float fg = shm.g.u.s3.gtile[cb32 + 4];
          const float gg = shm.g.u.s3.gtile[cb32 + 8];
          const float og = shm.g.u.s3.gtile[cb32 + 12];
          const float cold = cb[b*512 + j];
          const float cnew = sigm(fg)*cold + sigm(ig)*tanh_(gg);
          hv[t2] = sigm(og)*tanh_(cnew);
          cb[b*512 + j] = cnew;
        }
        const int j0 = wg*8 + jj2*2;
        union { float f[2]; u64 u; } pk; pk.f[0] = hv[0]; pk.f[1] = hv[1];
        astu64((u64*)&hf[b*512 + j0], pk.u);
        const u32 pw = (u32)f2bf(hv[0]) | ((u32)f2bf(hv[1]) << 16);
        astu32((u32*)&hfw[fragIdx(b, j0)], pw);
      }
    } else if (wg < 128) {
      if (s > 0) writer(ws, in_mask, dout, wg - 64, tid, s - 1);
    }
    bt += 256;
    gbar(ws, bt);

    // ================= PHASE 2: dx + flash attention chunk =================
    {
      const int b = wg >> 2, ch = wg & 3;
      const float* hf = (const float*)(ws + OFF_HF);
      const u16* W2b = (const u16*)(ws + OFF_W2B);
      if (tid < 512) shm.p2.hstage[tid] = aldf(&hf[b*512 + tid]);
      __syncthreads();
      {  // dx = relu(h[b]@W2 + b2), redundant per chunk-WG
        const int n = tid & 255, q = tid >> 8;
        float acc = 0.f;
        #pragma unroll 4
        for (int k = q*128; k < q*128 + 128; ++k)
          acc = fmaf(shm.p2.hstage[k], bf2f(W2b[k*256 + n]), acc);
        shm.p2.red[q*256 + n] = acc;
      }
      __syncthreads();
      if (tid < 256) shm.p2.dxl[tid] = fmaxf(shm.p2.red[tid] + shm.p2.red[256+tid] + shm.p2.red[512+tid] + shm.p2.red[768+tid] + b2[tid], 0.f);
      __syncthreads();

      const int hl = tid & 31;
      const int unit = tid >> 5;
      float dxv[8];
      #pragma unroll
      for (int j2 = 0; j2 < 8; ++j2) dxv[j2] = shm.p2.dxl[hl*8 + j2];
      const u16* kt = (const u16*)(ws + OFF_KT);
      const u16* vw = (const u16*)(ws + OFF_VW);
      const float* s0 = (const float*)(ws + OFF_S0);
      // preload all 8 rows (non-temporal: keep L2 for weights)
      u16x8 kvr[8]; u16x4 vvr[8]; float s0r[8];
      #pragma unroll
      for (int i = 0; i < 8; ++i) {
        const int l = ch*256 + i*32 + unit;
        const size_t row = (size_t)b*1024 + l;
        kvr[i] = __builtin_nontemporal_load((const u16x8*)(kt + row*256 + hl*8));
        vvr[i] = __builtin_nontemporal_load((const u16x4*)(vw + row*128 + hl*4));
        s0r[i] = s0[row];
      }
      float m = -1e30f, S = 0.f, cx0 = 0.f, cx1 = 0.f, cx2 = 0.f, cx3 = 0.f, keep = 0.f;
      #pragma unroll
      for (int i = 0; i < 8; ++i) {
        float sum = 0.f;
        #pragma unroll
        for (int j2 = 0; j2 < 8; ++j2) sum = fmaf(bf2f(kvr[i][j2]), dxv[j2], sum);
        #pragma unroll
        for (int d = 1; d < 32; d <<= 1) sum += __shfl_xor(sum, d, 64);
        const float sc = sum + s0r[i];
        if (hl == i) keep = sc;
        const float mn = fmaxf(m, sc);
        const float cf = __expf(m - mn);
        const float e  = __expf(sc - mn);
        S = S*cf + e;
        cx0 *= cf; cx1 *= cf; cx2 *= cf; cx3 *= cf;
        m = mn;
        cx0 = fmaf(e, bf2f(vvr[i][0]), cx0);
        cx1 = fmaf(e, bf2f(vvr[i][1]), cx1);
        cx2 = fmaf(e, bf2f(vvr[i][2]), cx2);
        cx3 = fmaf(e, bf2f(vvr[i][3]), cx3);
      }
      if (hl < 8) astf(&((float*)(ws + OFF_SC))[b*1024 + ch*256 + hl*32 + unit], keep);
      shm.p2.mrg[unit*132 + 4 + hl*4 + 0] = cx0;
      shm.p2.mrg[unit*132 + 4 + hl*4 + 1] = cx1;
      shm.p2.mrg[unit*132 + 4 + hl*4 + 2] = cx2;
      shm.p2.mrg[unit*132 + 4 + hl*4 + 3] = cx3;
      if (hl == 0) { shm.p2.mrg[unit*132] = m; shm.p2.mrg[unit*132+1] = S; }
      __syncthreads();
      if (tid < 128) {
        float mg = -1e30f;
        for (int u = 0; u < 32; ++u) mg = fmaxf(mg, shm.p2.mrg[u*132]);
        float Sg = 0.f, cx = 0.f;
        for (int u = 0; u < 32; ++u) {
          const float f = __expf(shm.p2.mrg[u*132] - mg);
          Sg = fmaf(shm.p2.mrg[u*132+1], f, Sg);
          cx = fmaf(f, shm.p2.mrg[u*132 + 4 + tid], cx);
        }
        astf(&part[(b*4+ch)*130 + 2 + tid], cx);
        if (tid == 0) { astf(&part[(b*4+ch)*130], mg); astf(&part[(b*4+ch)*130+1], Sg); }
      }
    }
    bt += 256;
    gbar(ws, bt);
  }
  // epilogue: write step 1023 outputs
  if (wg >= 64 && wg < 128) writer(ws, in_mask, dout, wg - 64, tid, 1023);
}

extern "C" void kernel_launch(void* const* d_in, const int* in_sizes, int n_in,
                              void* d_out, int out_size, void* d_ws, size_t ws_size,
                              hipStream_t stream)
{
  (void)in_sizes; (void)n_in; (void)out_size; (void)ws_size;
  const float* hid_r  = (const float*)d_in[0];
  const float* in_mask= (const float*)d_in[1];
  const float* init_in= (const float*)d_in[2];
  const float* h0     = (const float*)d_in[3];
  const float* c0     = (const float*)d_in[4];
  const float* W1     = (const float*)d_in[5];
  const float* b1     = (const float*)d_in[6];
  const float* Wih    = (const float*)d_in[7];
  const float* Whh    = (const float*)d_in[8];
  const float* bih    = (const float*)d_in[9];
  const float* bhh    = (const float*)d_in[10];
  const float* W2     = (const float*)d_in[11];
  const float* b2     = (const float*)d_in[12];
  const float* Wq     = (const float*)d_in[13];
  const float* bq     = (const float*)d_in[14];
  const float* Wk     = (const float*)d_in[15];
  const float* bk     = (const float*)d_in[16];
  const float* Wv     = (const float*)d_in[17];
  const float* bv     = (const float*)d_in[18];
  const float* W3     = (const float*)d_in[19];
  const float* b3     = (const float*)d_in[20];
  char* ws = (char*)d_ws;
  float* out = (float*)d_out;

  hipLaunchKernelGGL(kPrep, dim3(410), dim3(256), 0, stream, ws,
                     W1, Wih, Whh, W2, Wq, bq, Wk, bk, Wv, bv, W3, b3, bih, bhh, c0, h0);
  hipLaunchKernelGGL(kKTVW, dim3(2048), dim3(256), 0, stream, ws, hid_r, in_mask);

  void* args[] = {(void*)&ws, (void*)&init_in, (void*)&in_mask, (void*)&b1, (void*)&b2, (void*)&out};
  hipLaunchCooperativeKernel((void*)kMain, dim3(256), dim3(1024), args, 0, stream);
}

// Round 4
// 76924.377 us; speedup vs baseline: 3.4100x; 1.1264x over previous
//
#include <hip/hip_runtime.h>

typedef unsigned short u16;
typedef unsigned int u32;
typedef unsigned long long u64;
typedef __attribute__((ext_vector_type(8))) short bf16x8;
typedef __attribute__((ext_vector_type(8))) unsigned short u16x8;
typedef __attribute__((ext_vector_type(4))) unsigned short u16x4;
typedef __attribute__((ext_vector_type(4))) float f32x4;

#define DI static __device__ __forceinline__

// ---------------- workspace layout (bytes) ----------------
constexpr size_t OFF_WKQ  = 0;                               // 256x256 f32  (scale*Wk@Wq^T)
constexpr size_t OFF_WVW  = OFF_WKQ  + 256*256*4;            // 256x128 f32  (Wv@W3)
constexpr size_t OFF_WB   = OFF_WVW  + 256*128*4;            // 256 f32      (scale*Wk@bq)
constexpr size_t OFF_BYV  = OFF_WB   + 256*4;                // 128 f32      (b3 + bv@W3)
constexpr size_t OFF_BG   = OFF_BYV  + 128*4;                // 2048 f32     (bih+bhh)
constexpr size_t OFF_W2B  = OFF_BG   + 2048*4;               // 512x256 bf16
constexpr size_t OFF_W1F  = OFF_W2B  + 512*256*2;            // 16*4*64*8 bf16 (frag-swizzled W1)
constexpr size_t OFF_WIHF = OFF_W1F  + 16*4*64*8*2;          // 128*8*64*8 bf16
constexpr size_t OFF_WHHF = OFF_WIHF + 128*8*64*8*2;         // 128*16*64*8 bf16
constexpr size_t OFF_KT   = OFF_WHHF + 128*16*64*8*2;        // 64*1024*256 bf16
constexpr size_t OFF_VW   = OFF_KT   + (size_t)64*1024*256*2;// 64*1024*128 bf16
constexpr size_t OFF_S0   = OFF_VW   + (size_t)64*1024*128*2;// 65536 f32 (incl. mask bias)
constexpr size_t OFF_CB   = OFF_S0   + 65536*4;              // 64x512 f32 cell state (WG-private)
constexpr size_t OFF_HF   = OFF_CB   + 64*512*4;             // 64x512 f32 h          (cross-WG, bypass)
constexpr size_t OFF_HFR  = OFF_HF   + 64*512*4;             // 2 x (16*4*64*8) bf16  (cross-WG, bypass)
constexpr size_t OFF_SC   = OFF_HFR  + 2*16*4*64*8*2;        // 64x1024 f32 raw scores(cross-WG, bypass)
constexpr size_t OFF_PART = OFF_SC   + 64*1024*4;            // 64x4x130 f32          (cross-WG, bypass)
constexpr size_t OFF_FLG  = OFF_PART + 64*4*130*4;           // 256 u32 arrival flags (1 KB)
constexpr size_t OFF_REL  = OFF_FLG  + 256*4;                // 1 u32 release word (own line)

DI float bf2f(u16 u){ unsigned int v = ((unsigned int)u) << 16; return __uint_as_float(v); }
DI u16 f2bf(float f){ unsigned int u = __float_as_uint(f); unsigned int r = (u + 0x7FFFu + ((u>>16)&1u)) >> 16; return (u16)r; }
DI float sigm(float x){ return 1.f/(1.f + __expf(-x)); }
DI float tanh_(float x){ return 1.f - 2.f/(__expf(2.f*x) + 1.f); }

// ---- L2-bypassing (agent-scope, relaxed) accessors for cross-WG data ----
DI float aldf(const float* p){ return __hip_atomic_load(p, __ATOMIC_RELAXED, __HIP_MEMORY_SCOPE_AGENT); }
DI void  astf(float* p, float v){ __hip_atomic_store(p, v, __ATOMIC_RELAXED, __HIP_MEMORY_SCOPE_AGENT); }
DI void  astu32(u32* p, u32 v){ __hip_atomic_store(p, v, __ATOMIC_RELAXED, __HIP_MEMORY_SCOPE_AGENT); }
DI u32   aldu32(const u32* p){ return __hip_atomic_load(p, __ATOMIC_RELAXED, __HIP_MEMORY_SCOPE_AGENT); }
DI void  astu64(u64* p, u64 v){ __hip_atomic_store(p, v, __ATOMIC_RELAXED, __HIP_MEMORY_SCOPE_AGENT); }
DI u64   aldu64(const u64* p){ return __hip_atomic_load(p, __ATOMIC_RELAXED, __HIP_MEMORY_SCOPE_AGENT); }

union FragU { u64 u[2]; bf16x8 v; };
DI bf16x8 ald_frag(const u16* p){
  FragU r; const u64* q = (const u64*)p;
  r.u[0] = aldu64(q); r.u[1] = aldu64(q+1);
  return r.v;
}

// frag slot for an A-operand element [row m][k]: lane=(m&15)|(((k>>3)&3)<<4), i=k&7, ktile=k>>5, mtile=m>>4
DI int fragIdx(int m, int k){ return (((k>>5)*4 + (m>>4))*64 + ((m&15) | (((k>>3)&3)<<4)))*8 + (k&7); }

// ---- grid barrier: per-WG flag stores + single aggregator + release word. NO RMW anywhere. ----
// Data visibility: __syncthreads() drains each wave's vmcnt (sc1 stores complete at MALL)
// before thread0 publishes the arrival flag.
DI void gbar(char* ws, int wg, unsigned e){
  __syncthreads();
  u32* flags = (u32*)(ws + OFF_FLG);
  u32* rel   = (u32*)(ws + OFF_REL);
  if (threadIdx.x == 0) astu32(&flags[wg], e);
  if (wg == 0 && threadIdx.x < 64) {
    const int l4 = (int)threadIdx.x * 4;
    for (;;) {
      const u32 f0 = aldu32(&flags[l4+0]);
      const u32 f1 = aldu32(&flags[l4+1]);
      const u32 f2 = aldu32(&flags[l4+2]);
      const u32 f3 = aldu32(&flags[l4+3]);
      if (__all(f0 >= e && f1 >= e && f2 >= e && f3 >= e)) break;
    }
    if (threadIdx.x == 0) astu32(rel, e);
  }
  if (threadIdx.x == 0) {
    while (aldu32(rel) < e) __builtin_amdgcn_s_sleep(2);
  }
  __syncthreads();
}

// ---------------- one-time weight prep ----------------
__global__ __launch_bounds__(256) void kPrep(char* ws,
    const float* W1, const float* Wih, const float* Whh, const float* W2,
    const float* Wq, const float* bq, const float* Wk, const float* bk,
    const float* Wv, const float* bv, const float* W3, const float* b3,
    const float* bih, const float* bhh, const float* c0, const float* h0)
{
  const int wg = blockIdx.x, tid = threadIdx.x;
  if (wg < 64) {                       // Wkq[e][d] = scale * dot(Wk row e, Wq row d)
    float* Wkq = (float*)(ws + OFF_WKQ);
    for (int rr = 0; rr < 4; ++rr) {
      const int e = wg*4 + rr;
      float acc = 0.f;
      for (int d = 0; d < 256; ++d) acc = fmaf(Wk[e*256+d], Wq[tid*256+d], acc);
      Wkq[e*256 + tid] = acc * 0.0625f;
    }
  } else if (wg < 96) {                // Wvw[e][o] = dot(Wv row e, W3 col o)
    float* Wvw = (float*)(ws + OFF_WVW);
    if (tid < 128) {
      for (int rr = 0; rr < 8; ++rr) {
        const int e = (wg-64)*8 + rr;
        float acc = 0.f;
        for (int d = 0; d < 256; ++d) acc = fmaf(Wv[e*256+d], W3[d*128+tid], acc);
        Wvw[e*128 + tid] = acc;
      }
    }
  } else if (wg == 96) {               // wb, byv
    float* wb = (float*)(ws + OFF_WB);
    float acc = 0.f;
    for (int d = 0; d < 256; ++d) acc = fmaf(Wk[tid*256+d], bq[d], acc);
    wb[tid] = acc * 0.0625f;
    if (tid < 128) {
      float* byv = (float*)(ws + OFF_BYV);
      float a2 = b3[tid];
      for (int d = 0; d < 256; ++d) a2 = fmaf(bv[d], W3[d*128+tid], a2);
      byv[tid] = a2;
    }
  } else if (wg == 97) {               // bg = bih + bhh; zero barrier flags + release (replay determinism)
    float* bg = (float*)(ws + OFF_BG);
    for (int j = tid; j < 2048; j += 256) bg[j] = bih[j] + bhh[j];
    if (tid < 64) {
      u32* flags = (u32*)(ws + OFF_FLG);
      for (int j = tid; j < 257; j += 64) flags[j] = 0u;   // flags[0..255] + rel
    }
  } else if (wg < 106) {               // W2 -> bf16
    u16* W2b = (u16*)(ws + OFF_W2B);
    const int r0 = (wg - 98)*64;
    for (int rr = 0; rr < 64; ++rr) W2b[(r0+rr)*256 + tid] = f2bf(W2[(r0+rr)*256 + tid]);
  } else if (wg < 122) {               // W1 frag swizzle (B-operand)
    u16* W1f = (u16*)(ws + OFF_W1F);
    const int nt2 = wg - 106;
    for (int idx = tid; idx < 4*512; idx += 256) {
      const int kt2 = idx >> 9, rem = idx & 511, lane = rem >> 3, i = rem & 7;
      const int k = kt2*32 + (lane>>4)*8 + i, n = nt2*16 + (lane&15);
      W1f[((nt2*4+kt2)*64+lane)*8+i] = f2bf(W1[k*256+n]);
    }
  } else if (wg < 250) {               // Wih frag swizzle, gate-interleaved col permutation
    u16* Wihf = (u16*)(ws + OFF_WIHF);
    const int nt = wg - 122;
    for (int idx = tid; idx < 8*512; idx += 256) {
      const int kt = idx >> 9, rem = idx & 511, lane = rem >> 3, i = rem & 7;
      const int k = kt*32 + (lane>>4)*8 + i, r = lane & 15;
      const int gcol = (r>>2)*512 + nt*4 + (r&3);   // r: 0..3=i,4..7=f,8..11=g,12..15=o
      Wihf[((nt*8+kt)*64+lane)*8+i] = f2bf(Wih[k*2048 + gcol]);
    }
  } else if (wg < 378) {               // Whh frag swizzle
    u16* Whhf = (u16*)(ws + OFF_WHHF);
    const int nt = wg - 250;
    for (int idx = tid; idx < 16*512; idx += 256) {
      const int kt = idx >> 9, rem = idx & 511, lane = rem >> 3, i = rem & 7;
      const int k = kt*32 + (lane>>4)*8 + i, r = lane & 15;
      const int gcol = (r>>2)*512 + nt*4 + (r&3);
      Whhf[((nt*16+kt)*64+lane)*8+i] = f2bf(Whh[k*2048 + gcol]);
    }
  } else if (wg < 410) {               // state init: c0 -> cbuf, h0 -> hfrag[0]
    float* cb = (float*)(ws + OFF_CB);
    u16* hfr0 = (u16*)(ws + OFF_HFR);
    const int base = (wg - 378)*1024;
    for (int ii = tid; ii < 1024; ii += 256) {
      const int idx = base + ii, b = idx >> 9, j = idx & 511;
      cb[idx] = c0[idx];
      hfr0[fragIdx(b, j)] = f2bf(h0[idx]);
    }
  }
}

// ---------------- precompute kt, vw, s0 (mask bias folded in) ----------------
__global__ __launch_bounds__(256) void kKTVW(char* __restrict__ ws, const float* __restrict__ hid_r,
                                             const float* __restrict__ in_mask)
{
  const int wg = blockIdx.x, tid = threadIdx.x;
  __shared__ float lh[256*36];  // [e][r], padded to 36
  const float* Wkq = (const float*)(ws + OFF_WKQ);
  const float* Wvw = (const float*)(ws + OFF_WVW);
  const float* wb  = (const float*)(ws + OFF_WB);
  u16* kt = (u16*)(ws + OFF_KT);
  u16* vw = (u16*)(ws + OFF_VW);
  float* s0 = (float*)(ws + OFF_S0);
  const size_t r0 = (size_t)wg * 32;
  for (int idx = tid; idx < 32*256; idx += 256) {
    const int e = idx & 255, r = idx >> 8;
    lh[e*36 + r] = hid_r[(r0 + r)*256 + e];
  }
  __syncthreads();
  float acc[32];
  #pragma unroll
  for (int r = 0; r < 32; ++r) acc[r] = 0.f;
  for (int e = 0; e < 256; ++e) {
    const float wv = Wkq[e*256 + tid];
    #pragma unroll
    for (int r4 = 0; r4 < 8; ++r4) {
      const float4 l4 = *(const float4*)&lh[e*36 + r4*4];
      acc[r4*4+0] = fmaf(l4.x, wv, acc[r4*4+0]);
      acc[r4*4+1] = fmaf(l4.y, wv, acc[r4*4+1]);
      acc[r4*4+2] = fmaf(l4.z, wv, acc[r4*4+2]);
      acc[r4*4+3] = fmaf(l4.w, wv, acc[r4*4+3]);
    }
  }
  for (int r = 0; r < 32; ++r) kt[(r0 + r)*256 + tid] = f2bf(acc[r]);
  if (tid < 128) {
    #pragma unroll
    for (int r = 0; r < 32; ++r) acc[r] = 0.f;
    for (int e = 0; e < 256; ++e) {
      const float wv = Wvw[e*128 + tid];
      #pragma unroll
      for (int r4 = 0; r4 < 8; ++r4) {
        const float4 l4 = *(const float4*)&lh[e*36 + r4*4];
        acc[r4*4+0] = fmaf(l4.x, wv, acc[r4*4+0]);
        acc[r4*4+1] = fmaf(l4.y, wv, acc[r4*4+1]);
        acc[r4*4+2] = fmaf(l4.z, wv, acc[r4*4+2]);
        acc[r4*4+3] = fmaf(l4.w, wv, acc[r4*4+3]);
      }
    }
    for (int r = 0; r < 32; ++r) vw[(r0 + r)*128 + tid] = f2bf(acc[r]);
  } else if (tid < 160) {
    const int r = tid - 128;
    float a3 = 0.f;
    for (int e = 0; e < 256; ++e) a3 = fmaf(lh[e*36 + r], wb[e], a3);
    s0[r0 + r] = a3 + (in_mask[r0 + r] == 0.f ? -1e9f : 0.f);
  }
}

// ---------------- shared memory union for kMain ----------------
union Shm {
  struct {
    union {
      u16 yfrag[16*64*8];                                       // stages 1-2 (16 KB)
      struct { float gmerge[8*64*4]; float gtile[64*32]; } s3;  // stages 3-4 (16 KB)
    } u;
    union {
      u16 afrag[32*64*8];                                       // stages 2-3 (32 KB)
      float lfac[64*4];                                         // stage 1 only
    } v;
  } g;
  struct { float red[4*256]; float dxl[256]; float hstage[512]; float mrg[32*132]; } p2;
};

DI void writer(char* ws, const float* in_mask, float* dout, int b, int tid, int t)
{
  float* part = (float*)(ws + OFF_PART);
  float* scores = (float*)(ws + OFF_SC);
  float pm[4], pS[4], m = -1e30f;
  #pragma unroll
  for (int c = 0; c < 4; ++c) { pm[c] = aldf(&part[(b*4+c)*130]); pS[c] = aldf(&part[(b*4+c)*130+1]); m = fmaxf(m, pm[c]); }
  float Sv = 0.f;
  #pragma unroll
  for (int c = 0; c < 4; ++c) Sv += pS[c] * __expf(pm[c]-m);
  const float inv = 1.f / Sv;
  float* attn = dout + (size_t)64*1024*128;
  attn[((size_t)b*1024 + t)*1024 + tid] = __expf(aldf(&scores[b*1024 + tid]) - m) * inv;
  if (tid < 128) {
    const float* byv = (const float*)(ws + OFF_BYV);
    float a2 = 0.f;
    #pragma unroll
    for (int c = 0; c < 4; ++c) a2 += __expf(pm[c]-m) * aldf(&part[(b*4+c)*130+2+tid]);
    const float y = fmaxf(a2*inv + byv[tid], 0.f);
    dout[((size_t)b*1024 + t)*128 + tid] = y * in_mask[b*1024 + t];
  }
}

// ---------------- persistent kernel: whole scan, flag/aggregator barrier ----------------
__global__ __launch_bounds__(1024) void kMain(char* __restrict__ ws, const float* __restrict__ init_in,
    const float* __restrict__ in_mask, const float* __restrict__ b1, const float* __restrict__ b2,
    float* __restrict__ dout)
{
  const int wg = blockIdx.x, tid = threadIdx.x;
  __shared__ Shm shm;

  float* part = (float*)(ws + OFF_PART);
  const float* byv = (const float*)(ws + OFF_BYV);
  unsigned e = 0;

  for (int s = 0; s < 1024; ++s) {
    // ================= PHASE 1 =================
    if (wg < 64) {
      // ---- gates WG: owns h columns j = wg*8 .. wg*8+7 ----
      // stage 1: y -> yfrag
      if (s == 0) {
        for (int idx = tid; idx < 64*128; idx += 1024) {
          const int b = idx >> 7, d0 = idx & 127;
          shm.g.u.yfrag[fragIdx(b, d0)] = f2bf(init_in[b*128 + d0]);
        }
      } else {
        if (tid < 64) {
          const int b = tid;
          float pm[4], m = -1e30f;
          #pragma unroll
          for (int c = 0; c < 4; ++c) { pm[c] = aldf(&part[(b*4+c)*130]); m = fmaxf(m, pm[c]); }
          float Sv = 0.f, pf[4];
          #pragma unroll
          for (int c = 0; c < 4; ++c) { pf[c] = __expf(pm[c]-m); Sv += aldf(&part[(b*4+c)*130+1])*pf[c]; }
          const float inv = 1.f/Sv;
          #pragma unroll
          for (int c = 0; c < 4; ++c) shm.g.v.lfac[b*4+c] = pf[c]*inv;
        }
        __syncthreads();
        for (int idx = tid; idx < 64*128; idx += 1024) {
          const int b = idx >> 7, d0 = idx & 127;
          float a2 = byv[d0];
          #pragma unroll
          for (int c = 0; c < 4; ++c) a2 += shm.g.v.lfac[b*4+c]*aldf(&part[(b*4+c)*130+2+d0]);
          shm.g.u.yfrag[fragIdx(b, d0)] = f2bf(fmaxf(a2, 0.f));
        }
      }
      __syncthreads();
      const int w = tid >> 6, lane = tid & 63;
      // stage 2: a = relu(y@W1 + b1); 16 waves cover 64 (mt,nt2) tiles
      {
        const u16* W1f = (const u16*)(ws + OFF_W1F);
        const int mt = w & 3, nb0 = w >> 2;
        for (int k = 0; k < 4; ++k) {
          const int nt2 = nb0 + k*4;
          f32x4 acc = {0.f,0.f,0.f,0.f};
          #pragma unroll
          for (int kt2 = 0; kt2 < 4; ++kt2) {
            bf16x8 av = *(const bf16x8*)&shm.g.u.yfrag[((kt2*4+mt)*64+lane)*8];
            bf16x8 bv = *(const bf16x8*)&W1f[((nt2*4+kt2)*64+lane)*8];
            acc = __builtin_amdgcn_mfma_f32_16x16x32_bf16(av, bv, acc, 0, 0, 0);
          }
          const int col = nt2*16 + (lane&15);
          const float bb = b1[col];
          #pragma unroll
          for (int i = 0; i < 4; ++i) {
            const int b = mt*16 + (lane>>4)*4 + i;
            shm.g.v.afrag[fragIdx(b, col)] = f2bf(fmaxf(acc[i] + bb, 0.f));
          }
        }
      }
      __syncthreads();
      // stage 3: gates 64x32 tile = a@Wih + h@Whh + bg; 16 waves: (mt, ntile, khalf)
      {
        const u16* Wihf = (const u16*)(ws + OFF_WIHF);
        const u16* Whhf = (const u16*)(ws + OFF_WHHF);
        const u16* hfr = (const u16*)(ws + OFF_HFR) + (size_t)(s & 1)*(16*4*64*8);
        const int mt = w & 3, ntile = (w>>2) & 1, khalf = w >> 3;
        const int nt = wg*2 + ntile;
        f32x4 acc = {0.f,0.f,0.f,0.f};
        if (khalf == 0) {
          for (int kt = 0; kt < 8; ++kt) {
            bf16x8 av = *(const bf16x8*)&shm.g.v.afrag[((kt*4+mt)*64+lane)*8];
            bf16x8 bv = *(const bf16x8*)&Wihf[((nt*8+kt)*64+lane)*8];
            acc = __builtin_amdgcn_mfma_f32_16x16x32_bf16(av, bv, acc, 0, 0, 0);
          }
          for (int kt = 0; kt < 4; ++kt) {
            bf16x8 av = ald_frag(&hfr[((kt*4+mt)*64+lane)*8]);
            bf16x8 bv = *(const bf16x8*)&Whhf[((nt*16+kt)*64+lane)*8];
            acc = __builtin_amdgcn_mfma_f32_16x16x32_bf16(av, bv, acc, 0, 0, 0);
          }
        } else {
          for (int kt = 4; kt < 16; ++kt) {
            bf16x8 av = ald_frag(&hfr[((kt*4+mt)*64+lane)*8]);
            bf16x8 bv = *(const bf16x8*)&Whhf[((nt*16+kt)*64+lane)*8];
            acc = __builtin_amdgcn_mfma_f32_16x16x32_bf16(av, bv, acc, 0, 0, 0);
          }
        }
        __syncthreads();   // afrag reads done; s3 region (aliases yfrag) now writable
        if (khalf == 1) {
          #pragma unroll
          for (int i = 0; i < 4; ++i) shm.g.u.s3.gmerge[((ntile*4+mt)*64+lane)*4+i] = acc[i];
        }
        __syncthreads();
        if (khalf == 0) {
          const float* bg = (const float*)(ws + OFF_BG);
          const int r = lane & 15;
          const float bb = bg[(r>>2)*512 + nt*4 + (r&3)];
          #pragma unroll
          for (int i = 0; i < 4; ++i) {
            const int b = mt*16 + (lane>>4)*4 + i;
            shm.g.u.s3.gtile[b*32 + ntile*16 + r] = acc[i] + shm.g.u.s3.gmerge[((ntile*4+mt)*64+lane)*4+i] + bb;
          }
        }
      }
      __syncthreads();
      // stage 4: h,c pointwise; 256 threads x 2 cols -> packed bypass stores
      if (tid < 256) {
        const int b = tid >> 2, jj2 = tid & 3;
        float* cb = (float*)(ws + OFF_CB);
        float* hf = (float*)(ws + OFF_HF);
        u16* hfw = (u16*)(ws + OFF_HFR) + (size_t)((s & 1) ^ 1)*(16*4*64*8);
        float hv[2];
        #pragma unroll
        for (int t2 = 0; t2 < 2; ++t2) {
          const int jj = jj2*2 + t2;
          const int j = wg*8 + jj;
          const int cb32 = b*32 + (jj>>2)*16 + (jj&3);
          const float ig = shm.g.u.s3.gtile[cb32 + 0];
          const float fg = shm.g.u.s3.gtile[cb32 + 4];
          const float gg = shm.g.u.s3.gtile[cb32 + 8];
          const float og = shm.g.u.s3.gtile[cb32 + 12];
          const float cold = cb[b*512 + j];
          const float cnew = sigm(fg)*cold + sigm(ig)*tanh_(gg);
          hv[t2] = sigm(og)*tanh_(cnew);
          cb[b*512 + j] = cnew;
        }
        const int j0 = wg*8 + jj2*2;
        union { float f[2]; u64 u; } pk; pk.f[0] = hv[0]; pk.f[1] = hv[1];
        astu64((u64*)&hf[b*512 + j0], pk.u);
        const u32 pw = (u32)f2bf(hv[0]) | ((u32)f2bf(hv[1]) << 16);
        astu32((u32*)&hfw[fragIdx(b, j0)], pw);
      }
    } else if (wg < 128) {
      if (s > 0) writer(ws, in_mask, dout, wg - 64, tid, s - 1);
    }
    gbar(ws, wg, ++e);

    // ================= PHASE 2: dx + flash attention chunk =================
    {
      const int b = wg >> 2, ch = wg & 3;
      const float* hf = (const float*)(ws + OFF_HF);
      const u16* W2b = (const u16*)(ws + OFF_W2B);
      if (tid < 512) shm.p2.hstage[tid] = aldf(&hf[b*512 + tid]);
      __syncthreads();
      {  // dx = relu(h[b]@W2 + b2), redundant per chunk-WG
        const int n = tid & 255, q = tid >> 8;
        float acc = 0.f;
        #pragma unroll 4
        for (int k = q*128; k < q*128 + 128; ++k)
          acc = fmaf(shm.p2.hstage[k], bf2f(W2b[k*256 + n]), acc);
        shm.p2.red[q*256 + n] = acc;
      }
      __syncthreads();
      if (tid < 256) shm.p2.dxl[tid] = fmaxf(shm.p2.red[tid] + shm.p2.red[256+tid] + shm.p2.red[512+tid] + shm.p2.red[768+tid] + b2[tid], 0.f);
      __syncthreads();

      const int hl = tid & 31;
      const int unit = tid >> 5;
      float dxv[8];
      #pragma unroll
      for (int j2 = 0; j2 < 8; ++j2) dxv[j2] = shm.p2.dxl[hl*8 + j2];
      const u16* kt = (const u16*)(ws + OFF_KT);
      const u16* vw = (const u16*)(ws + OFF_VW);
      const float* s0 = (const float*)(ws + OFF_S0);
      // preload all 8 rows (plain cached loads: chunk is WG-resident in L2/L3)
      u16x8 kvr[8]; u16x4 vvr[8]; float s0r[8];
      #pragma unroll
      for (int i = 0; i < 8; ++i) {
        const int l = ch*256 + i*32 + unit;
        const size_t row = (size_t)b*1024 + l;
        kvr[i] = *(const u16x8*)(kt + row*256 + hl*8);
        vvr[i] = *(const u16x4*)(vw + row*128 + hl*4);
        s0r[i] = s0[row];
      }
      float m = -1e30f, S = 0.f, cx0 = 0.f, cx1 = 0.f, cx2 = 0.f, cx3 = 0.f, keep = 0.f;
      #pragma unroll
      for (int i = 0; i < 8; ++i) {
        float sum = 0.f;
        #pragma unroll
        for (int j2 = 0; j2 < 8; ++j2) sum = fmaf(bf2f(kvr[i][j2]), dxv[j2], sum);
        #pragma unroll
        for (int d = 1; d < 32; d <<= 1) sum += __shfl_xor(sum, d, 64);
        const float sc = sum + s0r[i];
        if (hl == i) keep = sc;
        const float mn = fmaxf(m, sc);
        const float cf = __expf(m - mn);
        const float e2 = __expf(sc - mn);
        S = S*cf + e2;
        cx0 *= cf; cx1 *= cf; cx2 *= cf; cx3 *= cf;
        m = mn;
        cx0 = fmaf(e2, bf2f(vvr[i][0]), cx0);
        cx1 = fmaf(e2, bf2f(vvr[i][1]), cx1);
        cx2 = fmaf(e2, bf2f(vvr[i][2]), cx2);
        cx3 = fmaf(e2, bf2f(vvr[i][3]), cx3);
      }
      if (hl < 8) astf(&((float*)(ws + OFF_SC))[b*1024 + ch*256 + hl*32 + unit], keep);
      shm.p2.mrg[unit*132 + 4 + hl*4 + 0] = cx0;
      shm.p2.mrg[unit*132 + 4 + hl*4 + 1] = cx1;
      shm.p2.mrg[unit*132 + 4 + hl*4 + 2] = cx2;
      shm.p2.mrg[unit*132 + 4 + hl*4 + 3] = cx3;
      if (hl == 0) { shm.p2.mrg[unit*132] = m; shm.p2.mrg[unit*132+1] = S; }
      __syncthreads();
      if (tid < 128) {
        float mg = -1e30f;
        for (int u = 0; u < 32; ++u) mg = fmaxf(mg, shm.p2.mrg[u*132]);
        float Sg = 0.f, cx = 0.f;
        for (int u = 0; u < 32; ++u) {
          const float f = __expf(shm.p2.mrg[u*132] - mg);
          Sg = fmaf(shm.p2.mrg[u*132+1], f, Sg);
          cx = fmaf(f, shm.p2.mrg[u*132 + 4 + tid], cx);
        }
        astf(&part[(b*4+ch)*130 + 2 + tid], cx);
        if (tid == 0) { astf(&part[(b*4+ch)*130], mg); astf(&part[(b*4+ch)*130+1], Sg); }
      }
    }
    gbar(ws, wg, ++e);
  }
  // epilogue: write step 1023 outputs
  if (wg >= 64 && wg < 128) writer(ws, in_mask, dout, wg - 64, tid, 1023);
}

extern "C" void kernel_launch(void* const* d_in, const int* in_sizes, int n_in,
                              void* d_out, int out_size, void* d_ws, size_t ws_size,
                              hipStream_t stream)
{
  (void)in_sizes; (void)n_in; (void)out_size; (void)ws_size;
  const float* hid_r  = (const float*)d_in[0];
  const float* in_mask= (const float*)d_in[1];
  const float* init_in= (const float*)d_in[2];
  const float* h0     = (const float*)d_in[3];
  const float* c0     = (const float*)d_in[4];
  const float* W1     = (const float*)d_in[5];
  const float* b1     = (const float*)d_in[6];
  const float* Wih    = (const float*)d_in[7];
  const float* Whh    = (const float*)d_in[8];
  const float* bih    = (const float*)d_in[9];
  const float* bhh    = (const float*)d_in[10];
  const float* W2     = (const float*)d_in[11];
  const float* b2     = (const float*)d_in[12];
  const float* Wq     = (const float*)d_in[13];
  const float* bq     = (const float*)d_in[14];
  const float* Wk     = (const float*)d_in[15];
  const float* bk     = (const float*)d_in[16];
  const float* Wv     = (const float*)d_in[17];
  const float* bv     = (const float*)d_in[18];
  const float* W3     = (const float*)d_in[19];
  const float* b3     = (const float*)d_in[20];
  char* ws = (char*)d_ws;
  float* out = (float*)d_out;

  hipLaunchKernelGGL(kPrep, dim3(410), dim3(256), 0, stream, ws,
                     W1, Wih, Whh, W2, Wq, bq, Wk, bk, Wv, bv, W3, b3, bih, bhh, c0, h0);
  hipLaunchKernelGGL(kKTVW, dim3(2048), dim3(256), 0, stream, ws, hid_r, in_mask);

  void* args[] = {(void*)&ws, (void*)&init_in, (void*)&in_mask, (void*)&b1, (void*)&b2, (void*)&out};
  hipLaunchCooperativeKernel((void*)kMain, dim3(256), dim3(1024), args, 0, stream);
}

// Round 5
// 33762.787 us; speedup vs baseline: 7.7693x; 2.2784x over previous
//
#include <hip/hip_runtime.h>

typedef unsigned short u16;
typedef unsigned int u32;
typedef __attribute__((ext_vector_type(8))) short bf16x8;
typedef __attribute__((ext_vector_type(8))) unsigned short u16x8;
typedef __attribute__((ext_vector_type(4))) unsigned short u16x4;
typedef __attribute__((ext_vector_type(4))) float f32x4;

#define DI static __device__ __forceinline__

// ---------------- workspace layout (bytes) ----------------
constexpr size_t OFF_WKQ  = 0;                               // 256x256 f32  (scale*Wk@Wq^T)
constexpr size_t OFF_WVW  = OFF_WKQ  + 256*256*4;            // 256x128 f32  (Wv@W3)
constexpr size_t OFF_WB   = OFF_WVW  + 256*128*4;            // 256 f32      (scale*Wk@bq)
constexpr size_t OFF_BYV  = OFF_WB   + 256*4;                // 128 f32      (b3 + bv@W3)
constexpr size_t OFF_BG   = OFF_BYV  + 128*4;                // 2048 f32     (bih+bhh)
constexpr size_t OFF_W2B  = OFF_BG   + 2048*4;               // 512x256 bf16
constexpr size_t OFF_W1F  = OFF_W2B  + 512*256*2;            // 16*4*64*8 bf16 (frag-swizzled W1)
constexpr size_t OFF_WIHF = OFF_W1F  + 16*4*64*8*2;          // 128*8*64*8 bf16
constexpr size_t OFF_WHHF = OFF_WIHF + 128*8*64*8*2;         // 128*16*64*8 bf16
constexpr size_t OFF_KT   = OFF_WHHF + 128*16*64*8*2;        // 64*1024*256 bf16
constexpr size_t OFF_VW   = OFF_KT   + (size_t)64*1024*256*2;// 64*1024*128 bf16
constexpr size_t OFF_S0   = OFF_VW   + (size_t)64*1024*128*2;// 65536 f32 (incl. mask bias)
constexpr size_t OFF_CB   = OFF_S0   + 65536*4;              // 64x512 f32 cell state
constexpr size_t OFF_HF   = OFF_CB   + 64*512*4;             // 64x512 f32 h
constexpr size_t OFF_HFR  = OFF_HF   + 64*512*4;             // 2 x (16*4*64*8) bf16 h frags (ping-pong)
constexpr size_t OFF_SC   = OFF_HFR  + 2*16*4*64*8*2;        // 2 x 64x1024 f32 raw scores (ping-pong)
constexpr size_t OFF_PART = OFF_SC   + 2*64*1024*4;          // 2 x 64x4x130 f32 (m,S,ctx[128]) (ping-pong)

DI float bf2f(u16 u){ unsigned int v = ((unsigned int)u) << 16; return __uint_as_float(v); }
DI u16 f2bf(float f){ unsigned int u = __float_as_uint(f); unsigned int r = (u + 0x7FFFu + ((u>>16)&1u)) >> 16; return (u16)r; }
DI float sigm(float x){ return 1.f/(1.f + __expf(-x)); }
DI float tanh_(float x){ return 1.f - 2.f/(__expf(2.f*x) + 1.f); }

// frag slot for an A-operand element [row m][k]: lane=(m&15)|(((k>>3)&3)<<4), i=k&7, ktile=k>>5, mtile=m>>4
DI int fragIdx(int m, int k){ return (((k>>5)*4 + (m>>4))*64 + ((m&15) | (((k>>3)&3)<<4)))*8 + (k&7); }

// ---------------- one-time weight prep ----------------
__global__ __launch_bounds__(256) void kPrep(char* ws,
    const float* W1, const float* Wih, const float* Whh, const float* W2,
    const float* Wq, const float* bq, const float* Wk, const float* bk,
    const float* Wv, const float* bv, const float* W3, const float* b3,
    const float* bih, const float* bhh, const float* c0, const float* h0)
{
  const int wg = blockIdx.x, tid = threadIdx.x;
  if (wg < 64) {                       // Wkq[e][d] = scale * dot(Wk row e, Wq row d)
    float* Wkq = (float*)(ws + OFF_WKQ);
    for (int rr = 0; rr < 4; ++rr) {
      const int e = wg*4 + rr;
      float acc = 0.f;
      for (int d = 0; d < 256; ++d) acc = fmaf(Wk[e*256+d], Wq[tid*256+d], acc);
      Wkq[e*256 + tid] = acc * 0.0625f;
    }
  } else if (wg < 96) {                // Wvw[e][o] = dot(Wv row e, W3 col o)
    float* Wvw = (float*)(ws + OFF_WVW);
    if (tid < 128) {
      for (int rr = 0; rr < 8; ++rr) {
        const int e = (wg-64)*8 + rr;
        float acc = 0.f;
        for (int d = 0; d < 256; ++d) acc = fmaf(Wv[e*256+d], W3[d*128+tid], acc);
        Wvw[e*128 + tid] = acc;
      }
    }
  } else if (wg == 96) {               // wb, byv
    float* wb = (float*)(ws + OFF_WB);
    float acc = 0.f;
    for (int d = 0; d < 256; ++d) acc = fmaf(Wk[tid*256+d], bq[d], acc);
    wb[tid] = acc * 0.0625f;
    if (tid < 128) {
      float* byv = (float*)(ws + OFF_BYV);
      float a2 = b3[tid];
      for (int d = 0; d < 256; ++d) a2 = fmaf(bv[d], W3[d*128+tid], a2);
      byv[tid] = a2;
    }
  } else if (wg == 97) {               // bg = bih + bhh
    float* bg = (float*)(ws + OFF_BG);
    for (int j = tid; j < 2048; j += 256) bg[j] = bih[j] + bhh[j];
  } else if (wg < 106) {               // W2 -> bf16
    u16* W2b = (u16*)(ws + OFF_W2B);
    const int r0 = (wg - 98)*64;
    for (int rr = 0; rr < 64; ++rr) W2b[(r0+rr)*256 + tid] = f2bf(W2[(r0+rr)*256 + tid]);
  } else if (wg < 122) {               // W1 frag swizzle (B-operand)
    u16* W1f = (u16*)(ws + OFF_W1F);
    const int nt2 = wg - 106;
    for (int idx = tid; idx < 4*512; idx += 256) {
      const int kt2 = idx >> 9, rem = idx & 511, lane = rem >> 3, i = rem & 7;
      const int k = kt2*32 + (lane>>4)*8 + i, n = nt2*16 + (lane&15);
      W1f[((nt2*4+kt2)*64+lane)*8+i] = f2bf(W1[k*256+n]);
    }
  } else if (wg < 250) {               // Wih frag swizzle, gate-interleaved col permutation
    u16* Wihf = (u16*)(ws + OFF_WIHF);
    const int nt = wg - 122;
    for (int idx = tid; idx < 8*512; idx += 256) {
      const int kt = idx >> 9, rem = idx & 511, lane = rem >> 3, i = rem & 7;
      const int k = kt*32 + (lane>>4)*8 + i, r = lane & 15;
      const int gcol = (r>>2)*512 + nt*4 + (r&3);   // r: 0..3=i,4..7=f,8..11=g,12..15=o
      Wihf[((nt*8+kt)*64+lane)*8+i] = f2bf(Wih[k*2048 + gcol]);
    }
  } else if (wg < 378) {               // Whh frag swizzle
    u16* Whhf = (u16*)(ws + OFF_WHHF);
    const int nt = wg - 250;
    for (int idx = tid; idx < 16*512; idx += 256) {
      const int kt = idx >> 9, rem = idx & 511, lane = rem >> 3, i = rem & 7;
      const int k = kt*32 + (lane>>4)*8 + i, r = lane & 15;
      const int gcol = (r>>2)*512 + nt*4 + (r&3);
      Whhf[((nt*16+kt)*64+lane)*8+i] = f2bf(Whh[k*2048 + gcol]);
    }
  } else if (wg < 410) {               // state init: c0 -> cbuf, h0 -> hfrag[0]
    float* cb = (float*)(ws + OFF_CB);
    u16* hfr0 = (u16*)(ws + OFF_HFR);
    const int base = (wg - 378)*1024;
    for (int ii = tid; ii < 1024; ii += 256) {
      const int idx = base + ii, b = idx >> 9, j = idx & 511;
      cb[idx] = c0[idx];
      hfr0[fragIdx(b, j)] = f2bf(h0[idx]);
    }
  }
}

// ---------------- precompute kt, vw, s0 (mask bias folded in) ----------------
__global__ __launch_bounds__(256) void kKTVW(char* __restrict__ ws, const float* __restrict__ hid_r,
                                             const float* __restrict__ in_mask)
{
  const int wg = blockIdx.x, tid = threadIdx.x;
  __shared__ float lh[256*36];  // [e][r], padded to 36
  const float* Wkq = (const float*)(ws + OFF_WKQ);
  const float* Wvw = (const float*)(ws + OFF_WVW);
  const float* wb  = (const float*)(ws + OFF_WB);
  u16* kt = (u16*)(ws + OFF_KT);
  u16* vw = (u16*)(ws + OFF_VW);
  float* s0 = (float*)(ws + OFF_S0);
  const size_t r0 = (size_t)wg * 32;
  for (int idx = tid; idx < 32*256; idx += 256) {
    const int e = idx & 255, r = idx >> 8;
    lh[e*36 + r] = hid_r[(r0 + r)*256 + e];
  }
  __syncthreads();
  float acc[32];
  #pragma unroll
  for (int r = 0; r < 32; ++r) acc[r] = 0.f;
  for (int e = 0; e < 256; ++e) {
    const float wv = Wkq[e*256 + tid];
    #pragma unroll
    for (int r4 = 0; r4 < 8; ++r4) {
      const float4 l4 = *(const float4*)&lh[e*36 + r4*4];
      acc[r4*4+0] = fmaf(l4.x, wv, acc[r4*4+0]);
      acc[r4*4+1] = fmaf(l4.y, wv, acc[r4*4+1]);
      acc[r4*4+2] = fmaf(l4.z, wv, acc[r4*4+2]);
      acc[r4*4+3] = fmaf(l4.w, wv, acc[r4*4+3]);
    }
  }
  for (int r = 0; r < 32; ++r) kt[(r0 + r)*256 + tid] = f2bf(acc[r]);
  if (tid < 128) {
    #pragma unroll
    for (int r = 0; r < 32; ++r) acc[r] = 0.f;
    for (int e = 0; e < 256; ++e) {
      const float wv = Wvw[e*128 + tid];
      #pragma unroll
      for (int r4 = 0; r4 < 8; ++r4) {
        const float4 l4 = *(const float4*)&lh[e*36 + r4*4];
        acc[r4*4+0] = fmaf(l4.x, wv, acc[r4*4+0]);
        acc[r4*4+1] = fmaf(l4.y, wv, acc[r4*4+1]);
        acc[r4*4+2] = fmaf(l4.z, wv, acc[r4*4+2]);
        acc[r4*4+3] = fmaf(l4.w, wv, acc[r4*4+3]);
      }
    }
    for (int r = 0; r < 32; ++r) vw[(r0 + r)*128 + tid] = f2bf(acc[r]);
  } else if (tid < 160) {
    const int r = tid - 128;
    float a3 = 0.f;
    for (int e = 0; e < 256; ++e) a3 = fmaf(lh[e*36 + r], wb[e], a3);
    s0[r0 + r] = a3 + (in_mask[r0 + r] == 0.f ? -1e9f : 0.f);
  }
}

// ---------------- kA: combine(s-1)->y->a->gates->h,c   (64 WGs x 1024 thr) ----------------
__global__ __launch_bounds__(1024) void kA(char* __restrict__ ws, const float* __restrict__ init_in,
                                           const float* __restrict__ b1, int s)
{
  const int wg = blockIdx.x, tid = threadIdx.x;
  __shared__ union {
    union {
      u16 yfrag[16*64*8];                                       // stages 1-2 (16 KB)
      struct { float gmerge[8*64*4]; float gtile[64*32]; } s3;  // stages 3-4 (16 KB)
    } u;
    // NOTE: v region is separate storage below
  } shmU;
  __shared__ union {
    u16 afrag[32*64*8];                                         // stages 2-3 (32 KB)
    float lfac[64*4];                                           // stage 1 only
  } shmV;

  const float* part = (const float*)(ws + OFF_PART) + (size_t)((s+1)&1)*(64*4*130);
  const float* byv = (const float*)(ws + OFF_BYV);

  // stage 1: y -> yfrag (bf16 A-operand layout)
  if (s == 0) {
    for (int idx = tid; idx < 64*128; idx += 1024) {
      const int b = idx >> 7, d0 = idx & 127;
      shmU.u.yfrag[fragIdx(b, d0)] = f2bf(init_in[b*128 + d0]);
    }
  } else {
    if (tid < 64) {
      const int b = tid;
      float pm[4], m = -1e30f;
      #pragma unroll
      for (int c = 0; c < 4; ++c) { pm[c] = part[(b*4+c)*130]; m = fmaxf(m, pm[c]); }
      float Sv = 0.f, pf[4];
      #pragma unroll
      for (int c = 0; c < 4; ++c) { pf[c] = __expf(pm[c]-m); Sv += part[(b*4+c)*130+1]*pf[c]; }
      const float inv = 1.f/Sv;
      #pragma unroll
      for (int c = 0; c < 4; ++c) shmV.lfac[b*4+c] = pf[c]*inv;
    }
    __syncthreads();
    for (int idx = tid; idx < 64*128; idx += 1024) {
      const int b = idx >> 7, d0 = idx & 127;
      float a2 = byv[d0];
      #pragma unroll
      for (int c = 0; c < 4; ++c) a2 += shmV.lfac[b*4+c]*part[(b*4+c)*130+2+d0];
      shmU.u.yfrag[fragIdx(b, d0)] = f2bf(fmaxf(a2, 0.f));
    }
  }
  __syncthreads();
  const int w = tid >> 6, lane = tid & 63;
  // stage 2: a = relu(y@W1 + b1); 16 waves cover 64 (mt,nt2) tiles
  {
    const u16* W1f = (const u16*)(ws + OFF_W1F);
    const int mt = w & 3, nb0 = w >> 2;
    for (int k = 0; k < 4; ++k) {
      const int nt2 = nb0 + k*4;
      f32x4 acc = {0.f,0.f,0.f,0.f};
      #pragma unroll
      for (int kt2 = 0; kt2 < 4; ++kt2) {
        bf16x8 av = *(const bf16x8*)&shmU.u.yfrag[((kt2*4+mt)*64+lane)*8];
        bf16x8 bv = *(const bf16x8*)&W1f[((nt2*4+kt2)*64+lane)*8];
        acc = __builtin_amdgcn_mfma_f32_16x16x32_bf16(av, bv, acc, 0, 0, 0);
      }
      const int col = nt2*16 + (lane&15);
      const float bb = b1[col];
      #pragma unroll
      for (int i = 0; i < 4; ++i) {
        const int b = mt*16 + (lane>>4)*4 + i;
        shmV.afrag[fragIdx(b, col)] = f2bf(fmaxf(acc[i] + bb, 0.f));
      }
    }
  }
  __syncthreads();
  // stage 3: gates 64x32 tile = a@Wih + h@Whh + bg; 16 waves: (mt, ntile, khalf)
  {
    const u16* Wihf = (const u16*)(ws + OFF_WIHF);
    const u16* Whhf = (const u16*)(ws + OFF_WHHF);
    const u16* hfr = (const u16*)(ws + OFF_HFR) + (size_t)(s & 1)*(16*4*64*8);
    const int mt = w & 3, ntile = (w>>2) & 1, khalf = w >> 3;
    const int nt = wg*2 + ntile;
    f32x4 acc = {0.f,0.f,0.f,0.f};
    if (khalf == 0) {
      for (int kt = 0; kt < 8; ++kt) {
        bf16x8 av = *(const bf16x8*)&shmV.afrag[((kt*4+mt)*64+lane)*8];
        bf16x8 bv = *(const bf16x8*)&Wihf[((nt*8+kt)*64+lane)*8];
        acc = __builtin_amdgcn_mfma_f32_16x16x32_bf16(av, bv, acc, 0, 0, 0);
      }
      for (int kt = 0; kt < 4; ++kt) {
        bf16x8 av = *(const bf16x8*)&hfr[((kt*4+mt)*64+lane)*8];
        bf16x8 bv = *(const bf16x8*)&Whhf[((nt*16+kt)*64+lane)*8];
        acc = __builtin_amdgcn_mfma_f32_16x16x32_bf16(av, bv, acc, 0, 0, 0);
      }
    } else {
      for (int kt = 4; kt < 16; ++kt) {
        bf16x8 av = *(const bf16x8*)&hfr[((kt*4+mt)*64+lane)*8];
        bf16x8 bv = *(const bf16x8*)&Whhf[((nt*16+kt)*64+lane)*8];
        acc = __builtin_amdgcn_mfma_f32_16x16x32_bf16(av, bv, acc, 0, 0, 0);
      }
      #pragma unroll
      for (int i = 0; i < 4; ++i) shmU.u.s3.gmerge[((ntile*4+mt)*64+lane)*4+i] = acc[i];
    }
    __syncthreads();
    if (khalf == 0) {
      const float* bg = (const float*)(ws + OFF_BG);
      const int r = lane & 15;
      const float bb = bg[(r>>2)*512 + nt*4 + (r&3)];
      #pragma unroll
      for (int i = 0; i < 4; ++i) {
        const int b = mt*16 + (lane>>4)*4 + i;
        shmU.u.s3.gtile[b*32 + ntile*16 + r] = acc[i] + shmU.u.s3.gmerge[((ntile*4+mt)*64+lane)*4+i] + bb;
      }
    }
  }
  __syncthreads();
  // stage 4: h,c pointwise; 256 threads x 2 cols -> packed stores
  if (tid < 256) {
    const int b = tid >> 2, jj2 = tid & 3;
    float* cb = (float*)(ws + OFF_CB);
    float* hf = (float*)(ws + OFF_HF);
    u16* hfw = (u16*)(ws + OFF_HFR) + (size_t)((s & 1) ^ 1)*(16*4*64*8);
    float hv[2];
    #pragma unroll
    for (int t2 = 0; t2 < 2; ++t2) {
      const int jj = jj2*2 + t2;
      const int j = wg*8 + jj;
      const int cb32 = b*32 + (jj>>2)*16 + (jj&3);
      const float ig = shmU.u.s3.gtile[cb32 + 0];
      const float fg = shmU.u.s3.gtile[cb32 + 4];
      const float gg = shmU.u.s3.gtile[cb32 + 8];
      const float og = shmU.u.s3.gtile[cb32 + 12];
      const float cold = cb[b*512 + j];
      const float cnew = sigm(fg)*cold + sigm(ig)*tanh_(gg);
      hv[t2] = sigm(og)*tanh_(cnew);
      cb[b*512 + j] = cnew;
    }
    const int j0 = wg*8 + jj2*2;
    *(float2*)&hf[b*512 + j0] = make_float2(hv[0], hv[1]);
    const u32 pw = (u32)f2bf(hv[0]) | ((u32)f2bf(hv[1]) << 16);
    *(u32*)&hfw[fragIdx(b, j0)] = pw;
  }
}

// ---------------- kB: writer(s-1) + dx + flash attention chunk (256 WGs x 1024 thr) ----------------
__global__ __launch_bounds__(1024) void kB(char* __restrict__ ws, const float* __restrict__ in_mask,
                                           const float* __restrict__ b2, float* __restrict__ dout, int s)
{
  const int wg = blockIdx.x, tid = threadIdx.x;
  const int b = wg >> 2, ch = wg & 3;
  __shared__ float red[4*256];
  __shared__ float dxl[256];
  __shared__ float hstage[512];
  __shared__ float mrg[32*132];
  const float* hf = (const float*)(ws + OFF_HF);
  const u16* W2b = (const u16*)(ws + OFF_W2B);
  float* partc = (float*)(ws + OFF_PART) + (size_t)(s&1)*(64*4*130);       // this step's partials
  float* scc   = (float*)(ws + OFF_SC)   + (size_t)(s&1)*(64*1024);        // this step's scores

  // ---- writer for step s-1 (independent of this step's compute) ----
  if (s > 0 && tid < 256) {
    const float* partp = (const float*)(ws + OFF_PART) + (size_t)((s+1)&1)*(64*4*130);
    const float* scp   = (const float*)(ws + OFF_SC)   + (size_t)((s+1)&1)*(64*1024);
    const int t = s - 1, l = ch*256 + tid;
    float pm[4], pS[4], m = -1e30f;
    #pragma unroll
    for (int c = 0; c < 4; ++c) { pm[c] = partp[(b*4+c)*130]; pS[c] = partp[(b*4+c)*130+1]; m = fmaxf(m, pm[c]); }
    float Sv = 0.f;
    #pragma unroll
    for (int c = 0; c < 4; ++c) Sv += pS[c] * __expf(pm[c]-m);
    const float inv = 1.f / Sv;
    float* attn = dout + (size_t)64*1024*128;
    attn[((size_t)b*1024 + t)*1024 + l] = __expf(scp[b*1024 + l] - m) * inv;
    if (ch == 0 && tid < 128) {
      const float* byv = (const float*)(ws + OFF_BYV);
      float a2 = 0.f;
      #pragma unroll
      for (int c = 0; c < 4; ++c) a2 += __expf(pm[c]-m) * partp[(b*4+c)*130+2+tid];
      const float y = fmaxf(a2*inv + byv[tid], 0.f);
      dout[((size_t)b*1024 + t)*128 + tid] = y * in_mask[b*1024 + t];
    }
  }

  // ---- dx = relu(h[b]@W2 + b2), redundant per chunk-WG ----
  if (tid < 512) hstage[tid] = hf[b*512 + tid];
  __syncthreads();
  {
    const int n = tid & 255, q = tid >> 8;
    float acc = 0.f;
    #pragma unroll 4
    for (int k = q*128; k < q*128 + 128; ++k)
      acc = fmaf(hstage[k], bf2f(W2b[k*256 + n]), acc);
    red[q*256 + n] = acc;
  }
  __syncthreads();
  if (tid < 256) dxl[tid] = fmaxf(red[tid] + red[256+tid] + red[512+tid] + red[768+tid] + b2[tid], 0.f);
  __syncthreads();

  // ---- flash attention over this WG's 256-key chunk ----
  const int hl = tid & 31;
  const int unit = tid >> 5;
  float dxv[8];
  #pragma unroll
  for (int j2 = 0; j2 < 8; ++j2) dxv[j2] = dxl[hl*8 + j2];
  const u16* kt = (const u16*)(ws + OFF_KT);
  const u16* vw = (const u16*)(ws + OFF_VW);
  const float* s0 = (const float*)(ws + OFF_S0);
  u16x8 kvr[8]; u16x4 vvr[8]; float s0r[8];
  #pragma unroll
  for (int i = 0; i < 8; ++i) {
    const int l = ch*256 + i*32 + unit;
    const size_t row = (size_t)b*1024 + l;
    kvr[i] = *(const u16x8*)(kt + row*256 + hl*8);
    vvr[i] = *(const u16x4*)(vw + row*128 + hl*4);
    s0r[i] = s0[row];
  }
  float m = -1e30f, S = 0.f, cx0 = 0.f, cx1 = 0.f, cx2 = 0.f, cx3 = 0.f, keep = 0.f;
  #pragma unroll
  for (int i = 0; i < 8; ++i) {
    float sum = 0.f;
    #pragma unroll
    for (int j2 = 0; j2 < 8; ++j2) sum = fmaf(bf2f(kvr[i][j2]), dxv[j2], sum);
    #pragma unroll
    for (int d = 1; d < 32; d <<= 1) sum += __shfl_xor(sum, d, 64);
    const float sc = sum + s0r[i];
    if (hl == i) keep = sc;
    const float mn = fmaxf(m, sc);
    const float cf = __expf(m - mn);
    const float e2 = __expf(sc - mn);
    S = S*cf + e2;
    cx0 *= cf; cx1 *= cf; cx2 *= cf; cx3 *= cf;
    m = mn;
    cx0 = fmaf(e2, bf2f(vvr[i][0]), cx0);
    cx1 = fmaf(e2, bf2f(vvr[i][1]), cx1);
    cx2 = fmaf(e2, bf2f(vvr[i][2]), cx2);
    cx3 = fmaf(e2, bf2f(vvr[i][3]), cx3);
  }
  if (hl < 8) scc[b*1024 + ch*256 + hl*32 + unit] = keep;
  mrg[unit*132 + 4 + hl*4 + 0] = cx0;
  mrg[unit*132 + 4 + hl*4 + 1] = cx1;
  mrg[unit*132 + 4 + hl*4 + 2] = cx2;
  mrg[unit*132 + 4 + hl*4 + 3] = cx3;
  if (hl == 0) { mrg[unit*132] = m; mrg[unit*132+1] = S; }
  __syncthreads();
  if (tid < 128) {   // merge 32 unit-partials -> chunk partial
    float mg = -1e30f;
    for (int u = 0; u < 32; ++u) mg = fmaxf(mg, mrg[u*132]);
    float Sg = 0.f, cx = 0.f;
    for (int u = 0; u < 32; ++u) {
      const float f = __expf(mrg[u*132] - mg);
      Sg = fmaf(mrg[u*132+1], f, Sg);
      cx = fmaf(f, mrg[u*132 + 4 + tid], cx);
    }
    partc[(b*4+ch)*130 + 2 + tid] = cx;
    if (tid == 0) { partc[(b*4+ch)*130] = mg; partc[(b*4+ch)*130+1] = Sg; }
  }
}

// ---------------- kWLast: writer for t=1023 (64 WGs x 1024 thr) ----------------
__global__ __launch_bounds__(1024) void kWLast(char* __restrict__ ws, const float* __restrict__ in_mask,
                                               float* __restrict__ dout)
{
  const int b = blockIdx.x, tid = threadIdx.x;
  const float* part = (const float*)(ws + OFF_PART) + (size_t)(1023&1)*(64*4*130);
  const float* sc   = (const float*)(ws + OFF_SC)   + (size_t)(1023&1)*(64*1024);
  float pm[4], pS[4], m = -1e30f;
  #pragma unroll
  for (int c = 0; c < 4; ++c) { pm[c] = part[(b*4+c)*130]; pS[c] = part[(b*4+c)*130+1]; m = fmaxf(m, pm[c]); }
  float Sv = 0.f;
  #pragma unroll
  for (int c = 0; c < 4; ++c) Sv += pS[c] * __expf(pm[c]-m);
  const float inv = 1.f / Sv;
  float* attn = dout + (size_t)64*1024*128;
  attn[((size_t)b*1024 + 1023)*1024 + tid] = __expf(sc[b*1024 + tid] - m) * inv;
  if (tid < 128) {
    const float* byv = (const float*)(ws + OFF_BYV);
    float a2 = 0.f;
    #pragma unroll
    for (int c = 0; c < 4; ++c) a2 += __expf(pm[c]-m) * part[(b*4+c)*130+2+tid];
    const float y = fmaxf(a2*inv + byv[tid], 0.f);
    dout[((size_t)b*1024 + 1023)*128 + tid] = y * in_mask[b*1024 + 1023];
  }
}

extern "C" void kernel_launch(void* const* d_in, const int* in_sizes, int n_in,
                              void* d_out, int out_size, void* d_ws, size_t ws_size,
                              hipStream_t stream)
{
  (void)in_sizes; (void)n_in; (void)out_size; (void)ws_size;
  const float* hid_r  = (const float*)d_in[0];
  const float* in_mask= (const float*)d_in[1];
  const float* init_in= (const float*)d_in[2];
  const float* h0     = (const float*)d_in[3];
  const float* c0     = (const float*)d_in[4];
  const float* W1     = (const float*)d_in[5];
  const float* b1     = (const float*)d_in[6];
  const float* Wih    = (const float*)d_in[7];
  const float* Whh    = (const float*)d_in[8];
  const float* bih    = (const float*)d_in[9];
  const float* bhh    = (const float*)d_in[10];
  const float* W2     = (const float*)d_in[11];
  const float* b2     = (const float*)d_in[12];
  const float* Wq     = (const float*)d_in[13];
  const float* bq     = (const float*)d_in[14];
  const float* Wk     = (const float*)d_in[15];
  const float* bk     = (const float*)d_in[16];
  const float* Wv     = (const float*)d_in[17];
  const float* bv     = (const float*)d_in[18];
  const float* W3     = (const float*)d_in[19];
  const float* b3     = (const float*)d_in[20];
  char* ws = (char*)d_ws;
  float* out = (float*)d_out;

  hipLaunchKernelGGL(kPrep, dim3(410), dim3(256), 0, stream, ws,
                     W1, Wih, Whh, W2, Wq, bq, Wk, bk, Wv, bv, W3, b3, bih, bhh, c0, h0);
  hipLaunchKernelGGL(kKTVW, dim3(2048), dim3(256), 0, stream, ws, hid_r, in_mask);
  for (int s = 0; s < 1024; ++s) {
    hipLaunchKernelGGL(kA, dim3(64), dim3(1024), 0, stream, ws, init_in, b1, s);
    hipLaunchKernelGGL(kB, dim3(256), dim3(1024), 0, stream, ws, in_mask, b2, out, s);
  }
  hipLaunchKernelGGL(kWLast, dim3(64), dim3(1024), 0, stream, ws, in_mask, out);
}